// Round 5
// baseline (699.856 us; speedup 1.0000x reference)
//
#include <hip/hip_runtime.h>
#include <math.h>

#define L_ 2
#define B_ 2
#define C_ 256
#define H_ 8
#define HD_ 32
#define T_ 16
#define S_ 512
#define DFF_ 1024
#define NTS (T_*S_)                 // 8192
#define NELEM ((size_t)B_*C_*T_*S_) // 4194304
#define QKM 512                     // fused Q|K output channels

typedef _Float16 half8v __attribute__((ext_vector_type(8)));
typedef _Float16 half4v __attribute__((ext_vector_type(4)));
typedef _Float16 half2v __attribute__((ext_vector_type(2)));
typedef float   float4v __attribute__((ext_vector_type(4)));

union h8u { half8v v; half2v h[4]; };

// ---------------- elementwise ----------------
__global__ void copy_kernel(const float* __restrict__ src, float* __restrict__ dst, int n4) {
    int i = blockIdx.x * blockDim.x + threadIdx.x;
    if (i < n4) ((float4*)dst)[i] = ((const float4*)src)[i];
}

__global__ void cvt_kernel(const float* __restrict__ s, _Float16* __restrict__ d, int n) {
    int i = blockIdx.x * blockDim.x + threadIdx.x;
    if (i < n) d[i] = (_Float16)s[i];
}

// stack Wq,Wk -> fp16 [L][512][256] (rows 0-255 = Wq, 256-511 = Wk)
__global__ void cvt_qk_kernel(const float* __restrict__ Wq, const float* __restrict__ Wk,
                              _Float16* __restrict__ out) {
    int i = blockIdx.x * 256 + threadIdx.x;      // L*512*256
    int k = i & 255;
    int m = (i >> 8) & 511;
    int l = i >> 17;
    float v = (m < 256) ? Wq[((size_t)l*256 + m)*256 + k]
                        : Wk[((size_t)l*256 + (m-256))*256 + k];
    out[i] = (_Float16)v;
}

__global__ void stack_bias_kernel(const float* __restrict__ bq, const float* __restrict__ bk,
                                  float* __restrict__ out) {
    int i = blockIdx.x * 256 + threadIdx.x;      // L*512
    int c = i & 255, sel = (i >> 8) & 1, l = i >> 9;
    out[i] = sel ? bk[l*256 + c] : bq[l*256 + c];
}

// ---------------- layernorm over C -> fp16 [b][ts][c] ----------------
template<bool HASPOS>
__global__ __launch_bounds__(256) void ln_t(const float* __restrict__ x,
                                            const float* __restrict__ gam,
                                            const float* __restrict__ bet,
                                            const float* __restrict__ pos,
                                            _Float16* __restrict__ s2,
                                            _Float16* __restrict__ qk) {
    __shared__ float redS[8][32];
    __shared__ float redQ[8][32];
    __shared__ _Float16 tiles[(HASPOS ? 2 : 1) * 32 * 256];
    _Float16* t0 = tiles;
    _Float16* t1 = tiles + 32 * 256;
    int tid = threadIdx.x;
    int nl = tid & 31, cg = tid >> 5;
    int gpos = blockIdx.x * 32;
    int b = gpos >> 13, nb = gpos & 8191;
    const float* xb = x + (size_t)b * C_ * NTS + nb + nl;
    float xv[32], pv[HASPOS ? 32 : 1];
    float sum = 0.f, sq = 0.f;
    #pragma unroll
    for (int j = 0; j < 32; ++j) {
        float v = xb[(size_t)(cg * 32 + j) * NTS];
        xv[j] = v; sum += v; sq += v * v;
    }
    if (HASPOS) {
        const float* pb = pos + (size_t)b * C_ * NTS + nb + nl;
        #pragma unroll
        for (int j = 0; j < 32; ++j) pv[j] = pb[(size_t)(cg * 32 + j) * NTS];
    }
    redS[cg][nl] = sum; redQ[cg][nl] = sq;
    __syncthreads();
    float s = 0.f, q = 0.f;
    #pragma unroll
    for (int g = 0; g < 8; ++g) { s += redS[g][nl]; q += redQ[g][nl]; }
    float mean = s * (1.0f / C_);
    float var  = q * (1.0f / C_) - mean * mean;
    float rstd = rsqrtf(var + 1e-5f);
    #pragma unroll
    for (int jj = 0; jj < 4; ++jj) {
        half8v h0, h1;
        #pragma unroll
        for (int j2 = 0; j2 < 8; ++j2) {
            int j = jj * 8 + j2;
            int c = cg * 32 + j;
            float y = (xv[j] - mean) * rstd * gam[c] + bet[c];
            h0[j2] = (_Float16)y;
            if (HASPOS) h1[j2] = (_Float16)(y + pv[j]);
        }
        int cs = (cg * 4 + jj) ^ nl;
        *(half8v*)(t0 + nl * 256 + cs * 8) = h0;
        if (HASPOS) *(half8v*)(t1 + nl * 256 + cs * 8) = h1;
    }
    __syncthreads();
    #pragma unroll
    for (int it = 0; it < 4; ++it) {
        int chunk = tid + it * 256;
        int row = chunk >> 5, ch = chunk & 31;
        int cs = ch ^ row;
        half8v v0 = *(half8v*)(t0 + row * 256 + cs * 8);
        *(half8v*)(s2 + (size_t)(gpos + row) * C_ + ch * 8) = v0;
        if (HASPOS) {
            half8v v1 = *(half8v*)(t1 + row * 256 + cs * 8);
            *(half8v*)(qk + (size_t)(gpos + row) * C_ + ch * 8) = v1;
        }
    }
}

// enc+pos -> fp16 transposed [b][ts][c]
__global__ __launch_bounds__(256) void addt_kernel(const float* __restrict__ a,
                                                   const float* __restrict__ p,
                                                   _Float16* __restrict__ o) {
    __shared__ _Float16 t0[32 * 256];
    int tid = threadIdx.x;
    int nl = tid & 31, cg = tid >> 5;
    int gpos = blockIdx.x * 32;
    int b = gpos >> 13, nb = gpos & 8191;
    const float* ab = a + (size_t)b * C_ * NTS + nb + nl;
    const float* pb = p + (size_t)b * C_ * NTS + nb + nl;
    float av[32], pv[32];
    #pragma unroll
    for (int j = 0; j < 32; ++j) av[j] = ab[(size_t)(cg * 32 + j) * NTS];
    #pragma unroll
    for (int j = 0; j < 32; ++j) pv[j] = pb[(size_t)(cg * 32 + j) * NTS];
    #pragma unroll
    for (int jj = 0; jj < 4; ++jj) {
        half8v h0;
        #pragma unroll
        for (int j2 = 0; j2 < 8; ++j2) {
            int j = jj * 8 + j2;
            h0[j2] = (_Float16)(av[j] + pv[j]);
        }
        int cs = (cg * 4 + jj) ^ nl;
        *(half8v*)(t0 + nl * 256 + cs * 8) = h0;
    }
    __syncthreads();
    #pragma unroll
    for (int it = 0; it < 4; ++it) {
        int chunk = tid + it * 256;
        int row = chunk >> 5, ch = chunk & 31;
        half8v v0 = *(half8v*)(t0 + row * 256 + (ch ^ row) * 8);
        *(half8v*)(o + (size_t)(gpos + row) * C_ + ch * 8) = v0;
    }
}

// ---------------- MFMA fp16 GEMM ----------------
// Y = W[M][K] * X^T  with X fp16 [b][N=8192][K].
// MODE 0: Y fp16 [b][n][M]; 1: dec f32 [b][M][N] +=; 2: relu, fp16 [b][n][M].
template<int MODE>
__global__ __launch_bounds__(256) void gemm_mfma(const _Float16* __restrict__ W,
                                                 const float* __restrict__ bias,
                                                 const _Float16* __restrict__ X,
                                                 void* __restrict__ Yv, int M, int K) {
    __shared__ _Float16 As[128 * 32];
    __shared__ _Float16 Bs[128 * 32];
    int b  = blockIdx.z;
    int m0 = blockIdx.y * 128;
    int n0 = blockIdx.x * 128;
    const _Float16* Xb = X + (size_t)b * NTS * K;
    int tid = threadIdx.x;
    int wave = tid >> 6, lane = tid & 63;
    int wm = (wave >> 1) * 64, wn = (wave & 1) * 64;
    int r = lane & 15, g = lane >> 4;
    float4v acc[4][4];
    #pragma unroll
    for (int i = 0; i < 4; ++i)
        #pragma unroll
        for (int j = 0; j < 4; ++j) acc[i][j] = (float4v){0.f, 0.f, 0.f, 0.f};

    for (int k0 = 0; k0 < K; k0 += 32) {
        #pragma unroll
        for (int it = 0; it < 2; ++it) {
            int c = tid + it * 256;
            int row = c >> 2, ch = c & 3;
            int sw = (ch ^ (row & 3)) << 3;
            *(half8v*)(As + row * 32 + sw) =
                *(const half8v*)(W + (size_t)(m0 + row) * K + k0 + ch * 8);
            *(half8v*)(Bs + row * 32 + sw) =
                *(const half8v*)(Xb + (size_t)(n0 + row) * K + k0 + ch * 8);
        }
        __syncthreads();
        half8v af[4], bf[4];
        #pragma unroll
        for (int mt = 0; mt < 4; ++mt) {
            int row = wm + mt * 16 + r;
            af[mt] = *(const half8v*)(As + row * 32 + ((g ^ (row & 3)) << 3));
        }
        #pragma unroll
        for (int nt = 0; nt < 4; ++nt) {
            int row = wn + nt * 16 + r;
            bf[nt] = *(const half8v*)(Bs + row * 32 + ((g ^ (row & 3)) << 3));
        }
        #pragma unroll
        for (int mt = 0; mt < 4; ++mt)
            #pragma unroll
            for (int nt = 0; nt < 4; ++nt)
                acc[mt][nt] = __builtin_amdgcn_mfma_f32_16x16x32_f16(af[mt], bf[nt], acc[mt][nt], 0, 0, 0);
        __syncthreads();
    }

    #pragma unroll
    for (int mt = 0; mt < 4; ++mt) {
        int m_base = m0 + wm + mt * 16 + g * 4;
        float bb[4];
        #pragma unroll
        for (int rr = 0; rr < 4; ++rr) bb[rr] = bias[m_base + rr];
        #pragma unroll
        for (int nt = 0; nt < 4; ++nt) {
            int n = n0 + wn + nt * 16 + r;
            if (MODE == 1) {
                float* Yd = (float*)Yv + (size_t)b * M * NTS;
                #pragma unroll
                for (int rr = 0; rr < 4; ++rr) {
                    size_t o = (size_t)(m_base + rr) * NTS + n;
                    Yd[o] += acc[mt][nt][rr] + bb[rr];
                }
            } else {
                _Float16* Y = (_Float16*)Yv + (size_t)b * NTS * M;
                half4v hv;
                #pragma unroll
                for (int rr = 0; rr < 4; ++rr) {
                    float v = acc[mt][nt][rr] + bb[rr];
                    if (MODE == 2) v = fmaxf(v, 0.f);
                    hv[rr] = (_Float16)v;
                }
                *(half4v*)(Y + (size_t)n * M + m_base) = hv;
            }
        }
    }
}

// ---------------- gate bits + unmasked count precompute ----------------
// gwb bit = near && unmasked; ucb = count of unmasked keys (per query row).
__global__ __launch_bounds__(256) void gate_kernel(const float* __restrict__ coord,
                                                   const int* __restrict__ mask,
                                                   unsigned long long* __restrict__ gwb,
                                                   int* __restrict__ ucb) {
    int wid  = blockIdx.x * 4 + (threadIdx.x >> 6);   // bt*512 + q
    int lane = threadIdx.x & 63;
    int q  = wid & 511;
    int bt = wid >> 9;
    const float* cb = coord + (size_t)bt * S_ * 3;
    const int* mrow = mask + (size_t)bt * S_;
    float cq0 = cb[q*3+0], cq1 = cb[q*3+1], cq2 = cb[q*3+2];
    int ucnt = 0;
    for (int i = 0; i < 8; ++i) {
        int k = i * 64 + lane;
        float dx = cq0 - cb[k*3+0];
        float dy = cq1 - cb[k*3+1];
        float dz = cq2 - cb[k*3+2];
        bool near = (dx*dx + dy*dy + dz*dz) < 625.0f;
        bool um = (mrow[k] == 0);
        unsigned long long g = __ballot(near && um);
        unsigned long long u = __ballot(um);
        if (lane == 0) {
            gwb[(size_t)wid*8 + i] = g;
            ucnt += __popcll(u);
        }
    }
    if (lane == 0) ucb[wid] = ucnt;
}

// ---------------- masked V column-sum partials ----------------
// Upar[(bt*4+p)*256 + c] = sum over s in [p*128,(p+1)*128) unmasked of vT[bt,s][c]
__global__ __launch_bounds__(256) void vsum_kernel(const _Float16* __restrict__ vT,
                                                   const int* __restrict__ mask,
                                                   float* __restrict__ Upar) {
    int blk = blockIdx.x;                 // B*T*4
    int p = blk & 3, bt = blk >> 2;
    int c = threadIdx.x;
    const _Float16* base = vT + ((size_t)bt * S_ + p * 128) * C_ + c;
    const int* mrow = mask + (size_t)bt * S_ + p * 128;
    float s = 0.f;
    #pragma unroll 8
    for (int r = 0; r < 128; ++r)
        if (mrow[r] == 0) s += (float)base[(size_t)r * C_];
    Upar[(size_t)blk * C_ + c] = s;
}

// ---------------- sparse distance-gated attention ----------------
// out = (U + sum_near (e-1)*V) / (u + sum_near (e-1))
// qk: fp16 [b][ts][512] (Q cols 0-255, K cols 256-511); v: fp16 [b][ts][256].
// K|V interleaved LDS rows, 144B stride (8 bank phases for random-row gathers).
__global__ __launch_bounds__(256) void attn_kernel(
        const _Float16* __restrict__ qk, const _Float16* __restrict__ v,
        const unsigned long long* __restrict__ gwb, const int* __restrict__ ucb,
        const float* __restrict__ Upar, _Float16* __restrict__ out) {
    __shared__ _Float16 KV[S_ * 72];    // 72 KB: row s = [K 32 | V 32 | pad 8]
    __shared__ float Ufin[HD_];
    int bid  = blockIdx.x;
    int half = bid & 1;
    int bht  = bid >> 1;
    int t = bht & (T_-1), h = (bht >> 4) & (H_-1), b = bht >> 7;
    int tid = threadIdx.x;
    int bt = b * T_ + t;
    const _Float16* kg = qk + ((size_t)bt * S_) * QKM + 256 + h * HD_;
    const _Float16* vg = v  + ((size_t)bt * S_) * C_  + h * HD_;

    // stage K|V rows
    #pragma unroll
    for (int it = 0; it < 8; ++it) {
        int c = tid + it * 256;
        int s = c >> 2, ch = c & 3;
        *(half8v*)(KV + s * 72 + ch * 8)      = *(const half8v*)(kg + (size_t)s * QKM + ch * 8);
        *(half8v*)(KV + s * 72 + 32 + ch * 8) = *(const half8v*)(vg + (size_t)s * C_ + ch * 8);
    }

    // fold U partials
    if (tid < HD_) {
        float s = 0.f;
        #pragma unroll
        for (int p = 0; p < 4; ++p)
            s += Upar[((size_t)bt * 4 + p) * C_ + h * HD_ + tid];
        Ufin[tid] = s;
    }

    int qi = half * 256 + tid;
    // query (fp16 pairs, unscaled)
    h8u qa[4];
    {
        const half8v* qp = (const half8v*)(qk + ((size_t)bt * S_ + qi) * QKM + h * HD_);
        #pragma unroll
        for (int i = 0; i < 4; ++i) qa[i].v = qp[i];
    }
    __syncthreads();

    const unsigned long long* gw8 = gwb + ((size_t)bt * S_ + qi) * 8;
    float O[HD_];
    #pragma unroll
    for (int d = 0; d < HD_; ++d) O[d] = 0.f;
    float l = (float)ucb[(size_t)bt * S_ + qi];

    for (int w = 0; w < 8; ++w) {
        unsigned long long gw = gw8[w];
        while (gw) {
            int j = __builtin_ctzll(gw);
            gw &= gw - 1;
            const _Float16* row = KV + (w * 64 + j) * 72;
            h8u k0, k1, k2, k3;
            k0.v = *(const half8v*)(row);
            k1.v = *(const half8v*)(row + 8);
            k2.v = *(const half8v*)(row + 16);
            k3.v = *(const half8v*)(row + 24);
            float s = 0.f;
            #pragma unroll
            for (int i = 0; i < 4; ++i) {
                s = __builtin_amdgcn_fdot2(k0.h[i], qa[0].h[i], s, false);
                s = __builtin_amdgcn_fdot2(k1.h[i], qa[1].h[i], s, false);
                s = __builtin_amdgcn_fdot2(k2.h[i], qa[2].h[i], s, false);
                s = __builtin_amdgcn_fdot2(k3.h[i], qa[3].h[i], s, false);
            }
            s *= 0.17677669529663687f;    // 1/sqrt(32)
            float e = __expf(fminf(s, 80.f));
            float em1 = e - 1.f;
            l += em1;
            half8v v0 = *(const half8v*)(row + 32);
            half8v v1 = *(const half8v*)(row + 40);
            half8v v2 = *(const half8v*)(row + 48);
            half8v v3 = *(const half8v*)(row + 56);
            #pragma unroll
            for (int d = 0; d < 8; ++d) {
                O[d]      = fmaf((float)v0[d], em1, O[d]);
                O[d + 8]  = fmaf((float)v1[d], em1, O[d + 8]);
                O[d + 16] = fmaf((float)v2[d], em1, O[d + 16]);
                O[d + 24] = fmaf((float)v3[d], em1, O[d + 24]);
            }
        }
    }
    float invl = 1.0f / l;
    float uf[HD_];
    #pragma unroll
    for (int d = 0; d < HD_; ++d) uf[d] = Ufin[d];
    _Float16* orow = out + ((size_t)bt * S_ + qi) * C_ + h * HD_;
    #pragma unroll
    for (int c0 = 0; c0 < 4; ++c0) {
        half8v hv;
        #pragma unroll
        for (int j = 0; j < 8; ++j)
            hv[j] = (_Float16)((O[c0*8+j] + uf[c0*8+j]) * invl);
        *(half8v*)(orow + c0 * 8) = hv;
    }
}

// ---------------- driver ----------------
extern "C" void kernel_launch(void* const* d_in, const int* in_sizes, int n_in,
                              void* d_out, int out_size, void* d_ws, size_t ws_size,
                              hipStream_t stream) {
    const float* decoder = (const float*)d_in[0];
    const float* encoder = (const float*)d_in[1];
    const float* pos     = (const float*)d_in[2];
    const float* coord   = (const float*)d_in[3];
    const int*   mask    = (const int*)d_in[4];
    const float* Wq = (const float*)d_in[5],  *bq = (const float*)d_in[6];
    const float* Wk = (const float*)d_in[7],  *bk = (const float*)d_in[8];
    const float* Wv = (const float*)d_in[9],  *bv = (const float*)d_in[10];
    const float* Wo = (const float*)d_in[11], *bo = (const float*)d_in[12];
    const float* W1 = (const float*)d_in[13], *b1 = (const float*)d_in[14];
    const float* W2 = (const float*)d_in[15], *b2 = (const float*)d_in[16];
    const float* ln_g = (const float*)d_in[17], *ln_b = (const float*)d_in[18];

    float* dec = (float*)d_out;

    size_t actsz = (size_t)B_ * NTS * C_;          // 4.19M halves
    _Float16* qkT  = (_Float16*)d_ws;              // 1 actsz (GEMM input)
    _Float16* qkT2 = qkT + actsz;                  // 2 actsz (fused Q|K output)
    _Float16* vT   = qkT2 + 2*actsz;               // 1 actsz
    _Float16* s2T  = vT + actsz;                   // 1 actsz (LN out / attn out)
    _Float16* hT   = qkT;                          // FFN hidden spans qkT..vT (4 actsz)
    _Float16* whqk = s2T + actsz;                  // L*512*256
    _Float16* whv  = whqk + (size_t)L_*QKM*C_;
    _Float16* who  = whv + (size_t)L_*C_*C_;
    _Float16* wh1  = who + (size_t)L_*C_*C_;
    _Float16* wh2  = wh1 + (size_t)L_*DFF_*C_;
    float* bqk = (float*)(wh2 + (size_t)L_*C_*DFF_);              // L*512 f32
    unsigned long long* gwb = (unsigned long long*)(bqk + L_*QKM);
    int* ucb = (int*)(gwb + (size_t)B_*T_*S_*8);
    float* Upar = (float*)(ucb + (size_t)B_*T_*S_);               // B*T*4*256 f32

    int n4 = (int)(NELEM / 4);
    dim3 ewGrid(n4 / 256);
    dim3 gGridQK(NTS/128, QKM/128, B_);   // (64, 4, 2)
    dim3 gGridC(NTS/128, C_/128, B_);     // (64, 2, 2)
    dim3 gGridF(NTS/128, DFF_/128, B_);   // (64, 8, 2)
    dim3 lnGrid(B_ * NTS / 32);
    dim3 attnGrid(B_ * H_ * T_ * 2);
    dim3 gateGrid(B_ * T_ * S_ / 4);
    dim3 vsumGrid(B_ * T_ * 4);

    copy_kernel<<<ewGrid, 256, 0, stream>>>(decoder, dec, n4);
    gate_kernel<<<gateGrid, 256, 0, stream>>>(coord, mask, gwb, ucb);
    int wqk = L_*QKM*C_, wn1 = L_*C_*C_, wn2 = L_*DFF_*C_;
    cvt_qk_kernel<<<wqk/256, 256, 0, stream>>>(Wq, Wk, whqk);
    stack_bias_kernel<<<(L_*QKM)/256, 256, 0, stream>>>(bq, bk, bqk);
    cvt_kernel<<<(wn1+255)/256, 256, 0, stream>>>(Wv, whv, wn1);
    cvt_kernel<<<(wn1+255)/256, 256, 0, stream>>>(Wo, who, wn1);
    cvt_kernel<<<(wn2+255)/256, 256, 0, stream>>>(W1, wh1, wn2);
    cvt_kernel<<<(wn2+255)/256, 256, 0, stream>>>(W2, wh2, wn2);

    for (int l = 0; l < L_; ++l) {
        const _Float16* whqk_l = whqk + (size_t)l*QKM*C_; const float* bqk_l = bqk + l*QKM;
        const _Float16* whv_l = whv + (size_t)l*C_*C_;  const float* bv_l = bv + l*C_;
        const _Float16* who_l = who + (size_t)l*C_*C_;  const float* bo_l = bo + l*C_;
        const _Float16* wh1_l = wh1 + (size_t)l*DFF_*C_; const float* b1_l = b1 + l*DFF_;
        const _Float16* wh2_l = wh2 + (size_t)l*C_*DFF_; const float* b2_l = b2 + l*C_;
        const float* g0 = ln_g + ((size_t)l*3 + 0)*C_; const float* e0 = ln_b + ((size_t)l*3 + 0)*C_;
        const float* g1 = ln_g + ((size_t)l*3 + 1)*C_; const float* e1 = ln_b + ((size_t)l*3 + 1)*C_;
        const float* g2 = ln_g + ((size_t)l*3 + 2)*C_; const float* e2 = ln_b + ((size_t)l*3 + 2)*C_;

        // ---- block A: self-attention, qk = LN(dec)+pos, v-input = LN(dec)
        ln_t<true><<<lnGrid, 256, 0, stream>>>(dec, g0, e0, pos, s2T, qkT);
        gemm_mfma<0><<<gGridQK, 256, 0, stream>>>(whqk_l, bqk_l, qkT, qkT2, QKM, C_);
        gemm_mfma<0><<<gGridC, 256, 0, stream>>>(whv_l, bv_l, s2T, vT, C_, C_);
        vsum_kernel<<<vsumGrid, 256, 0, stream>>>(vT, mask, Upar);
        attn_kernel<<<attnGrid, 256, 0, stream>>>(qkT2, vT, gwb, ucb, Upar, s2T);
        gemm_mfma<1><<<gGridC, 256, 0, stream>>>(who_l, bo_l, s2T, dec, C_, C_);

        // ---- block B: qk = encoder+pos, v-input = LN(dec)
        ln_t<false><<<lnGrid, 256, 0, stream>>>(dec, g1, e1, nullptr, s2T, nullptr);
        addt_kernel<<<lnGrid, 256, 0, stream>>>(encoder, pos, qkT);
        gemm_mfma<0><<<gGridQK, 256, 0, stream>>>(whqk_l, bqk_l, qkT, qkT2, QKM, C_);
        gemm_mfma<0><<<gGridC, 256, 0, stream>>>(whv_l, bv_l, s2T, vT, C_, C_);
        vsum_kernel<<<vsumGrid, 256, 0, stream>>>(vT, mask, Upar);
        attn_kernel<<<attnGrid, 256, 0, stream>>>(qkT2, vT, gwb, ucb, Upar, s2T);
        gemm_mfma<1><<<gGridC, 256, 0, stream>>>(who_l, bo_l, s2T, dec, C_, C_);

        // ---- FFN
        ln_t<false><<<lnGrid, 256, 0, stream>>>(dec, g2, e2, nullptr, s2T, nullptr);
        gemm_mfma<2><<<gGridF, 256, 0, stream>>>(wh1_l, b1_l, s2T, hT, DFF_, C_);
        gemm_mfma<1><<<gGridC, 256, 0, stream>>>(wh2_l, b2_l, hT, dec, C_, DFF_);
    }
}

// Round 6
// 569.326 us; speedup vs baseline: 1.2293x; 1.2293x over previous
//
#include <hip/hip_runtime.h>
#include <math.h>

#define L_ 2
#define B_ 2
#define C_ 256
#define H_ 8
#define HD_ 32
#define T_ 16
#define S_ 512
#define DFF_ 1024
#define NTS (T_*S_)                 // 8192
#define NELEM ((size_t)B_*C_*T_*S_) // 4194304
#define QKM 512                     // fused Q|K output channels

typedef _Float16 half8v __attribute__((ext_vector_type(8)));
typedef _Float16 half4v __attribute__((ext_vector_type(4)));
typedef _Float16 half2v __attribute__((ext_vector_type(2)));
typedef float   float4v __attribute__((ext_vector_type(4)));

union h8u { half8v v; half2v h[4]; };

// ---------------- fused weight prep: all cvts + bias stack in ONE dispatch ----
// whqk [L][512][256] (rows 0-255=Wq, 256-511=Wk); whv/who [L][256][256];
// wh1 [L][1024][256]; wh2 [L][256][1024]; bqk [L][512] f32.
__global__ void prep_kernel(const float* __restrict__ Wq, const float* __restrict__ Wk,
                            const float* __restrict__ Wv, const float* __restrict__ Wo,
                            const float* __restrict__ W1, const float* __restrict__ W2,
                            const float* __restrict__ bq, const float* __restrict__ bk,
                            _Float16* __restrict__ whqk, _Float16* __restrict__ whv,
                            _Float16* __restrict__ who, _Float16* __restrict__ wh1,
                            _Float16* __restrict__ wh2, float* __restrict__ bqk) {
    int i = blockIdx.x * 256 + threadIdx.x;
    const int NQK = L_*QKM*C_;      // 262144
    const int NCC = L_*C_*C_;       // 131072
    const int NFC = L_*DFF_*C_;     // 524288
    if (i < NQK) {
        int k = i & 255, m = (i >> 8) & 511, l = i >> 17;
        float v = (m < 256) ? Wq[((size_t)l*256 + m)*256 + k]
                            : Wk[((size_t)l*256 + (m-256))*256 + k];
        whqk[i] = (_Float16)v;
        return;
    }
    int j = i - NQK;
    if (j < NCC) { whv[j] = (_Float16)Wv[j]; return; }
    j -= NCC;
    if (j < NCC) { who[j] = (_Float16)Wo[j]; return; }
    j -= NCC;
    if (j < NFC) { wh1[j] = (_Float16)W1[j]; return; }
    j -= NFC;
    if (j < NFC) { wh2[j] = (_Float16)W2[j]; return; }
    j -= NFC;
    if (j < L_*QKM) {
        int c = j & 255, sel = (j >> 8) & 1, l = j >> 9;
        bqk[j] = sel ? bk[l*256 + c] : bq[l*256 + c];
    }
}

// ---------------- layernorm over C -> fp16 [b][ts][c] ----------------
template<bool HASPOS>
__global__ __launch_bounds__(256) void ln_t(const float* __restrict__ x,
                                            const float* __restrict__ gam,
                                            const float* __restrict__ bet,
                                            const float* __restrict__ pos,
                                            _Float16* __restrict__ s2,
                                            _Float16* __restrict__ qk) {
    __shared__ float redS[8][32];
    __shared__ float redQ[8][32];
    __shared__ _Float16 tiles[(HASPOS ? 2 : 1) * 32 * 256];
    _Float16* t0 = tiles;
    _Float16* t1 = tiles + 32 * 256;
    int tid = threadIdx.x;
    int nl = tid & 31, cg = tid >> 5;
    int gpos = blockIdx.x * 32;
    int b = gpos >> 13, nb = gpos & 8191;
    const float* xb = x + (size_t)b * C_ * NTS + nb + nl;
    float xv[32], pv[HASPOS ? 32 : 1];
    float sum = 0.f, sq = 0.f;
    #pragma unroll
    for (int j = 0; j < 32; ++j) {
        float v = xb[(size_t)(cg * 32 + j) * NTS];
        xv[j] = v; sum += v; sq += v * v;
    }
    if (HASPOS) {
        const float* pb = pos + (size_t)b * C_ * NTS + nb + nl;
        #pragma unroll
        for (int j = 0; j < 32; ++j) pv[j] = pb[(size_t)(cg * 32 + j) * NTS];
    }
    redS[cg][nl] = sum; redQ[cg][nl] = sq;
    __syncthreads();
    float s = 0.f, q = 0.f;
    #pragma unroll
    for (int g = 0; g < 8; ++g) { s += redS[g][nl]; q += redQ[g][nl]; }
    float mean = s * (1.0f / C_);
    float var  = q * (1.0f / C_) - mean * mean;
    float rstd = rsqrtf(var + 1e-5f);
    #pragma unroll
    for (int jj = 0; jj < 4; ++jj) {
        half8v h0, h1;
        #pragma unroll
        for (int j2 = 0; j2 < 8; ++j2) {
            int j = jj * 8 + j2;
            int c = cg * 32 + j;
            float y = (xv[j] - mean) * rstd * gam[c] + bet[c];
            h0[j2] = (_Float16)y;
            if (HASPOS) h1[j2] = (_Float16)(y + pv[j]);
        }
        int cs = (cg * 4 + jj) ^ nl;
        *(half8v*)(t0 + nl * 256 + cs * 8) = h0;
        if (HASPOS) *(half8v*)(t1 + nl * 256 + cs * 8) = h1;
    }
    __syncthreads();
    #pragma unroll
    for (int it = 0; it < 4; ++it) {
        int chunk = tid + it * 256;
        int row = chunk >> 5, ch = chunk & 31;
        int cs = ch ^ row;
        half8v v0 = *(half8v*)(t0 + row * 256 + cs * 8);
        *(half8v*)(s2 + (size_t)(gpos + row) * C_ + ch * 8) = v0;
        if (HASPOS) {
            half8v v1 = *(half8v*)(t1 + row * 256 + cs * 8);
            *(half8v*)(qk + (size_t)(gpos + row) * C_ + ch * 8) = v1;
        }
    }
}

// enc+pos -> fp16 transposed [b][ts][c]
__global__ __launch_bounds__(256) void addt_kernel(const float* __restrict__ a,
                                                   const float* __restrict__ p,
                                                   _Float16* __restrict__ o) {
    __shared__ _Float16 t0[32 * 256];
    int tid = threadIdx.x;
    int nl = tid & 31, cg = tid >> 5;
    int gpos = blockIdx.x * 32;
    int b = gpos >> 13, nb = gpos & 8191;
    const float* ab = a + (size_t)b * C_ * NTS + nb + nl;
    const float* pb = p + (size_t)b * C_ * NTS + nb + nl;
    float av[32], pv[32];
    #pragma unroll
    for (int j = 0; j < 32; ++j) av[j] = ab[(size_t)(cg * 32 + j) * NTS];
    #pragma unroll
    for (int j = 0; j < 32; ++j) pv[j] = pb[(size_t)(cg * 32 + j) * NTS];
    #pragma unroll
    for (int jj = 0; jj < 4; ++jj) {
        half8v h0;
        #pragma unroll
        for (int j2 = 0; j2 < 8; ++j2) {
            int j = jj * 8 + j2;
            h0[j2] = (_Float16)(av[j] + pv[j]);
        }
        int cs = (cg * 4 + jj) ^ nl;
        *(half8v*)(t0 + nl * 256 + cs * 8) = h0;
    }
    __syncthreads();
    #pragma unroll
    for (int it = 0; it < 4; ++it) {
        int chunk = tid + it * 256;
        int row = chunk >> 5, ch = chunk & 31;
        half8v v0 = *(half8v*)(t0 + row * 256 + (ch ^ row) * 8);
        *(half8v*)(o + (size_t)(gpos + row) * C_ + ch * 8) = v0;
    }
}

// ---------------- MFMA fp16 GEMM with direct-to-LDS staging ----------------
// Y = W[M][K] * X^T,  X fp16 [b][N=8192][K].
// MODE 0: Y fp16 [b][n][M]; 1: dst f32 [b][M][N] = src + acc; 2: relu fp16.
// Staging: global_load_lds width=16. The XOR chunk-swizzle is applied on the
// GLOBAL source side (within-64B-row permute keeps coalescing); LDS dest is
// wave-uniform base + lane*16 as the HW requires.
template<int MODE>
__global__ __launch_bounds__(256) void gemm_mfma(const _Float16* __restrict__ W,
                                                 const float* __restrict__ bias,
                                                 const _Float16* __restrict__ X,
                                                 const float* __restrict__ src,
                                                 void* __restrict__ Yv, int M, int K) {
    __shared__ _Float16 As[128 * 32];
    __shared__ _Float16 Bs[128 * 32];
    int b  = blockIdx.z;
    int m0 = blockIdx.y * 128;
    int n0 = blockIdx.x * 128;
    const _Float16* Xb = X + (size_t)b * NTS * K;
    int tid = threadIdx.x;
    int wave = tid >> 6, lane = tid & 63;
    int wm = (wave >> 1) * 64, wn = (wave & 1) * 64;
    int r = lane & 15, g = lane >> 4;
    float4v acc[4][4];
    #pragma unroll
    for (int i = 0; i < 4; ++i)
        #pragma unroll
        for (int j = 0; j < 4; ++j) acc[i][j] = (float4v){0.f, 0.f, 0.f, 0.f};

    for (int k0 = 0; k0 < K; k0 += 32) {
        #pragma unroll
        for (int it = 0; it < 2; ++it) {
            int cbase = wave * 64 + it * 256;        // wave-uniform chunk base
            int rowbase = cbase >> 2;                // 16 rows per wave-issue
            int row = rowbase + (lane >> 2);
            int ch = (lane & 3) ^ (row & 3);         // swizzle on global side
            const _Float16* ga = W  + (size_t)(m0 + row) * K + k0 + ch * 8;
            const _Float16* gb = Xb + (size_t)(n0 + row) * K + k0 + ch * 8;
            __builtin_amdgcn_global_load_lds(
                (const __attribute__((address_space(1))) void*)ga,
                (__attribute__((address_space(3))) void*)(As + rowbase * 32), 16, 0, 0);
            __builtin_amdgcn_global_load_lds(
                (const __attribute__((address_space(1))) void*)gb,
                (__attribute__((address_space(3))) void*)(Bs + rowbase * 32), 16, 0, 0);
        }
        __syncthreads();
        half8v af[4], bf[4];
        #pragma unroll
        for (int mt = 0; mt < 4; ++mt) {
            int row = wm + mt * 16 + r;
            af[mt] = *(const half8v*)(As + row * 32 + ((g ^ (row & 3)) << 3));
        }
        #pragma unroll
        for (int nt = 0; nt < 4; ++nt) {
            int row = wn + nt * 16 + r;
            bf[nt] = *(const half8v*)(Bs + row * 32 + ((g ^ (row & 3)) << 3));
        }
        #pragma unroll
        for (int mt = 0; mt < 4; ++mt)
            #pragma unroll
            for (int nt = 0; nt < 4; ++nt)
                acc[mt][nt] = __builtin_amdgcn_mfma_f32_16x16x32_f16(af[mt], bf[nt], acc[mt][nt], 0, 0, 0);
        __syncthreads();
    }

    // epilogue: C/D layout col(n)=lane&15, row(m)=(lane>>4)*4+reg
    #pragma unroll
    for (int mt = 0; mt < 4; ++mt) {
        int m_base = m0 + wm + mt * 16 + g * 4;
        float bb[4];
        #pragma unroll
        for (int rr = 0; rr < 4; ++rr) bb[rr] = bias[m_base + rr];
        #pragma unroll
        for (int nt = 0; nt < 4; ++nt) {
            int n = n0 + wn + nt * 16 + r;
            if (MODE == 1) {
                float* Yd = (float*)Yv + (size_t)b * M * NTS;
                const float* Sd = src + (size_t)b * M * NTS;
                #pragma unroll
                for (int rr = 0; rr < 4; ++rr) {
                    size_t o = (size_t)(m_base + rr) * NTS + n;
                    Yd[o] = Sd[o] + acc[mt][nt][rr] + bb[rr];
                }
            } else {
                _Float16* Y = (_Float16*)Yv + (size_t)b * NTS * M;
                half4v hv;
                #pragma unroll
                for (int rr = 0; rr < 4; ++rr) {
                    float v = acc[mt][nt][rr] + bb[rr];
                    if (MODE == 2) v = fmaxf(v, 0.f);
                    hv[rr] = (_Float16)v;
                }
                *(half4v*)(Y + (size_t)n * M + m_base) = hv;
            }
        }
    }
}

// ---------------- gate bits + counts precompute ----------------
// gwb bit = near && unmasked (per query row); ucb = #unmasked (per query row);
// umb = unmasked ballot words (per (b,t), query-independent).
__global__ __launch_bounds__(256) void gate_kernel(const float* __restrict__ coord,
                                                   const int* __restrict__ mask,
                                                   unsigned long long* __restrict__ gwb,
                                                   int* __restrict__ ucb,
                                                   unsigned long long* __restrict__ umb) {
    int wid  = blockIdx.x * 4 + (threadIdx.x >> 6);   // bt*512 + q
    int lane = threadIdx.x & 63;
    int q  = wid & 511;
    int bt = wid >> 9;
    const float* cb = coord + (size_t)bt * S_ * 3;
    const int* mrow = mask + (size_t)bt * S_;
    float cq0 = cb[q*3+0], cq1 = cb[q*3+1], cq2 = cb[q*3+2];
    int ucnt = 0;
    for (int i = 0; i < 8; ++i) {
        int k = i * 64 + lane;
        float dx = cq0 - cb[k*3+0];
        float dy = cq1 - cb[k*3+1];
        float dz = cq2 - cb[k*3+2];
        bool near = (dx*dx + dy*dy + dz*dz) < 625.0f;
        bool um = (mrow[k] == 0);
        unsigned long long gm = __ballot(near && um);
        unsigned long long un = __ballot(um);
        if (lane == 0) {
            gwb[(size_t)wid*8 + i] = gm;
            ucnt += __popcll(un);
            if (q == 0) umb[bt*8 + i] = un;
        }
    }
    if (lane == 0) ucb[wid] = ucnt;
}

// ---------------- sparse distance-gated attention (fused U) ----------------
// out = (U + sum_near (e-1)*V) / (u + sum_near (e-1));  U = sum_unmasked V.
// qk: fp16 [b][ts][512] (Q 0-255 | K 256-511); v: fp16 [b][ts][256].
// K|V interleaved LDS rows, 144B stride (8 bank phases for random gathers).
__global__ __launch_bounds__(256) void attn_kernel(
        const _Float16* __restrict__ qk, const _Float16* __restrict__ v,
        const unsigned long long* __restrict__ gwb, const int* __restrict__ ucb,
        const unsigned long long* __restrict__ umb, _Float16* __restrict__ out) {
    __shared__ _Float16 KV[S_ * 72];    // 72 KB: row s = [K 32 | V 32 | pad 8]
    __shared__ float Upart[8][32];
    __shared__ float Ufin[HD_];
    int bid  = blockIdx.x;
    int half = bid & 1;
    int bht  = bid >> 1;
    int t = bht & (T_-1), h = (bht >> 4) & (H_-1), b = bht >> 7;
    int tid = threadIdx.x;
    int bt = b * T_ + t;
    const _Float16* kg = qk + ((size_t)bt * S_) * QKM + 256 + h * HD_;
    const _Float16* vg = v  + ((size_t)bt * S_) * C_  + h * HD_;

    #pragma unroll
    for (int it = 0; it < 8; ++it) {
        int c = tid + it * 256;
        int s = c >> 2, ch = c & 3;
        *(half8v*)(KV + s * 72 + ch * 8)      = *(const half8v*)(kg + (size_t)s * QKM + ch * 8);
        *(half8v*)(KV + s * 72 + 32 + ch * 8) = *(const half8v*)(vg + (size_t)s * C_ + ch * 8);
    }

    int qi = half * 256 + tid;
    h8u qa[4];
    {
        const half8v* qp = (const half8v*)(qk + ((size_t)bt * S_ + qi) * QKM + h * HD_);
        #pragma unroll
        for (int i = 0; i < 4; ++i) qa[i].v = qp[i];
    }
    __syncthreads();

    // U partials: thread (d=tid&31, grp=tid>>5) sums its 64-key group
    {
        int d = tid & 31, grp = tid >> 5;
        unsigned long long um = umb[bt*8 + grp];
        float s = 0.f;
        for (int kk = 0; kk < 64; ++kk)
            if ((um >> kk) & 1) s += (float)KV[(grp*64 + kk) * 72 + 32 + d];
        Upart[grp][d] = s;
    }
    __syncthreads();
    if (tid < HD_) {
        float s = 0.f;
        #pragma unroll
        for (int gp = 0; gp < 8; ++gp) s += Upart[gp][tid];
        Ufin[tid] = s;
    }
    __syncthreads();

    const unsigned long long* gw8 = gwb + ((size_t)bt * S_ + qi) * 8;
    float O[HD_];
    #pragma unroll
    for (int d = 0; d < HD_; ++d) O[d] = 0.f;
    float l = (float)ucb[(size_t)bt * S_ + qi];

    for (int w = 0; w < 8; ++w) {
        unsigned long long gw = gw8[w];
        while (gw) {
            int j = __builtin_ctzll(gw);
            gw &= gw - 1;
            const _Float16* row = KV + (w * 64 + j) * 72;
            h8u k0, k1, k2, k3;
            k0.v = *(const half8v*)(row);
            k1.v = *(const half8v*)(row + 8);
            k2.v = *(const half8v*)(row + 16);
            k3.v = *(const half8v*)(row + 24);
            float s = 0.f;
            #pragma unroll
            for (int i = 0; i < 4; ++i) {
                s = __builtin_amdgcn_fdot2(k0.h[i], qa[0].h[i], s, false);
                s = __builtin_amdgcn_fdot2(k1.h[i], qa[1].h[i], s, false);
                s = __builtin_amdgcn_fdot2(k2.h[i], qa[2].h[i], s, false);
                s = __builtin_amdgcn_fdot2(k3.h[i], qa[3].h[i], s, false);
            }
            s *= 0.17677669529663687f;    // 1/sqrt(32)
            float e = __expf(fminf(s, 80.f));
            float em1 = e - 1.f;
            l += em1;
            half8v v0 = *(const half8v*)(row + 32);
            half8v v1 = *(const half8v*)(row + 40);
            half8v v2 = *(const half8v*)(row + 48);
            half8v v3 = *(const half8v*)(row + 56);
            #pragma unroll
            for (int d = 0; d < 8; ++d) {
                O[d]      = fmaf((float)v0[d], em1, O[d]);
                O[d + 8]  = fmaf((float)v1[d], em1, O[d + 8]);
                O[d + 16] = fmaf((float)v2[d], em1, O[d + 16]);
                O[d + 24] = fmaf((float)v3[d], em1, O[d + 24]);
            }
        }
    }
    float invl = 1.0f / l;
    _Float16* orow = out + ((size_t)bt * S_ + qi) * C_ + h * HD_;
    #pragma unroll
    for (int c0 = 0; c0 < 4; ++c0) {
        half8v hv;
        #pragma unroll
        for (int j = 0; j < 8; ++j)
            hv[j] = (_Float16)((O[c0*8+j] + Ufin[c0*8+j]) * invl);
        *(half8v*)(orow + c0 * 8) = hv;
    }
}

// ---------------- driver ----------------
extern "C" void kernel_launch(void* const* d_in, const int* in_sizes, int n_in,
                              void* d_out, int out_size, void* d_ws, size_t ws_size,
                              hipStream_t stream) {
    const float* decoder = (const float*)d_in[0];
    const float* encoder = (const float*)d_in[1];
    const float* pos     = (const float*)d_in[2];
    const float* coord   = (const float*)d_in[3];
    const int*   mask    = (const int*)d_in[4];
    const float* Wq = (const float*)d_in[5],  *bq = (const float*)d_in[6];
    const float* Wk = (const float*)d_in[7],  *bk = (const float*)d_in[8];
    const float* Wv = (const float*)d_in[9],  *bv = (const float*)d_in[10];
    const float* Wo = (const float*)d_in[11], *bo = (const float*)d_in[12];
    const float* W1 = (const float*)d_in[13], *b1 = (const float*)d_in[14];
    const float* W2 = (const float*)d_in[15], *b2 = (const float*)d_in[16];
    const float* ln_g = (const float*)d_in[17], *ln_b = (const float*)d_in[18];

    float* dec = (float*)d_out;

    size_t actsz = (size_t)B_ * NTS * C_;          // 4.19M halves
    _Float16* qkT  = (_Float16*)d_ws;              // 1 actsz (GEMM input)
    _Float16* qkT2 = qkT + actsz;                  // 2 actsz (fused Q|K output)
    _Float16* vT   = qkT2 + 2*actsz;               // 1 actsz
    _Float16* s2T  = vT + actsz;                   // 1 actsz (LN out / attn out)
    _Float16* hT   = qkT;                          // FFN hidden spans qkT..vT (4 actsz)
    _Float16* whqk = s2T + actsz;                  // L*512*256
    _Float16* whv  = whqk + (size_t)L_*QKM*C_;
    _Float16* who  = whv + (size_t)L_*C_*C_;
    _Float16* wh1  = who + (size_t)L_*C_*C_;
    _Float16* wh2  = wh1 + (size_t)L_*DFF_*C_;
    float* bqk = (float*)(wh2 + (size_t)L_*C_*DFF_);              // L*512 f32
    unsigned long long* gwb = (unsigned long long*)(bqk + L_*QKM);
    int* ucb = (int*)(gwb + (size_t)B_*T_*S_*8);
    unsigned long long* umb = (unsigned long long*)(ucb + (size_t)B_*T_*S_);

    dim3 gGridQK(NTS/128, QKM/128, B_);   // (64, 4, 2)
    dim3 gGridC(NTS/128, C_/128, B_);     // (64, 2, 2)
    dim3 gGridF(NTS/128, DFF_/128, B_);   // (64, 8, 2)
    dim3 lnGrid(B_ * NTS / 32);
    dim3 attnGrid(B_ * H_ * T_ * 2);
    dim3 gateGrid(B_ * T_ * S_ / 4);
    // prep total = 262144+131072+131072+524288+524288+1024 = 1573888 = 6148*256
    dim3 prepGrid(6148);

    gate_kernel<<<gateGrid, 256, 0, stream>>>(coord, mask, gwb, ucb, umb);
    prep_kernel<<<prepGrid, 256, 0, stream>>>(Wq, Wk, Wv, Wo, W1, W2, bq, bk,
                                              whqk, whv, who, wh1, wh2, bqk);

    for (int l = 0; l < L_; ++l) {
        const _Float16* whqk_l = whqk + (size_t)l*QKM*C_; const float* bqk_l = bqk + l*QKM;
        const _Float16* whv_l = whv + (size_t)l*C_*C_;  const float* bv_l = bv + l*C_;
        const _Float16* who_l = who + (size_t)l*C_*C_;  const float* bo_l = bo + l*C_;
        const _Float16* wh1_l = wh1 + (size_t)l*DFF_*C_; const float* b1_l = b1 + l*DFF_;
        const _Float16* wh2_l = wh2 + (size_t)l*C_*DFF_; const float* b2_l = b2 + l*C_;
        const float* g0 = ln_g + ((size_t)l*3 + 0)*C_; const float* e0 = ln_b + ((size_t)l*3 + 0)*C_;
        const float* g1 = ln_g + ((size_t)l*3 + 1)*C_; const float* e1 = ln_b + ((size_t)l*3 + 1)*C_;
        const float* g2 = ln_g + ((size_t)l*3 + 2)*C_; const float* e2 = ln_b + ((size_t)l*3 + 2)*C_;

        // layer 0 reads the pristine decoder input; dec becomes valid at the
        // first MODE-1 GEMM (which reads src=decoder and writes dec).
        const float* x0 = (l == 0) ? decoder : dec;
        const float* r0 = (l == 0) ? decoder : dec;

        // ---- block A: self-attention, qk = LN(x0)+pos, v-input = LN(x0)
        ln_t<true><<<lnGrid, 256, 0, stream>>>(x0, g0, e0, pos, s2T, qkT);
        gemm_mfma<0><<<gGridQK, 256, 0, stream>>>(whqk_l, bqk_l, qkT, nullptr, qkT2, QKM, C_);
        gemm_mfma<0><<<gGridC, 256, 0, stream>>>(whv_l, bv_l, s2T, nullptr, vT, C_, C_);
        attn_kernel<<<attnGrid, 256, 0, stream>>>(qkT2, vT, gwb, ucb, umb, s2T);
        gemm_mfma<1><<<gGridC, 256, 0, stream>>>(who_l, bo_l, s2T, r0, dec, C_, C_);

        // ---- block B: qk = encoder+pos, v-input = LN(dec)
        ln_t<false><<<lnGrid, 256, 0, stream>>>(dec, g1, e1, nullptr, s2T, nullptr);
        addt_kernel<<<lnGrid, 256, 0, stream>>>(encoder, pos, qkT);
        gemm_mfma<0><<<gGridQK, 256, 0, stream>>>(whqk_l, bqk_l, qkT, nullptr, qkT2, QKM, C_);
        gemm_mfma<0><<<gGridC, 256, 0, stream>>>(whv_l, bv_l, s2T, nullptr, vT, C_, C_);
        attn_kernel<<<attnGrid, 256, 0, stream>>>(qkT2, vT, gwb, ucb, umb, s2T);
        gemm_mfma<1><<<gGridC, 256, 0, stream>>>(who_l, bo_l, s2T, dec, dec, C_, C_);

        // ---- FFN
        ln_t<false><<<lnGrid, 256, 0, stream>>>(dec, g2, e2, nullptr, s2T, nullptr);
        gemm_mfma<2><<<gGridF, 256, 0, stream>>>(wh1_l, b1_l, s2T, nullptr, hT, DFF_, C_);
        gemm_mfma<1><<<gGridC, 256, 0, stream>>>(wh2_l, b2_l, hT, dec, dec, C_, DFF_);
    }
}

// Round 7
// 534.976 us; speedup vs baseline: 1.3082x; 1.0642x over previous
//
#include <hip/hip_runtime.h>
#include <math.h>

#define L_ 2
#define B_ 2
#define C_ 256
#define H_ 8
#define HD_ 32
#define T_ 16
#define S_ 512
#define DFF_ 1024
#define NTS (T_*S_)                 // 8192
#define NELEM ((size_t)B_*C_*T_*S_) // 4194304
#define QKM 512                     // fused Q|K output channels

typedef _Float16 half8v __attribute__((ext_vector_type(8)));
typedef _Float16 half4v __attribute__((ext_vector_type(4)));
typedef _Float16 half2v __attribute__((ext_vector_type(2)));
typedef float   float4v __attribute__((ext_vector_type(4)));

union h8u { half8v v; half2v h[4]; };

// ---------------- fused weight prep ----------------
__global__ void prep_kernel(const float* __restrict__ Wq, const float* __restrict__ Wk,
                            const float* __restrict__ Wv, const float* __restrict__ Wo,
                            const float* __restrict__ W1, const float* __restrict__ W2,
                            const float* __restrict__ bq, const float* __restrict__ bk,
                            _Float16* __restrict__ whqk, _Float16* __restrict__ whv,
                            _Float16* __restrict__ who, _Float16* __restrict__ wh1,
                            _Float16* __restrict__ wh2, float* __restrict__ bqk) {
    int i = blockIdx.x * 256 + threadIdx.x;
    const int NQK = L_*QKM*C_;      // 262144
    const int NCC = L_*C_*C_;       // 131072
    const int NFC = L_*DFF_*C_;     // 524288
    if (i < NQK) {
        int k = i & 255, m = (i >> 8) & 511, l = i >> 17;
        float v = (m < 256) ? Wq[((size_t)l*256 + m)*256 + k]
                            : Wk[((size_t)l*256 + (m-256))*256 + k];
        whqk[i] = (_Float16)v;
        return;
    }
    int j = i - NQK;
    if (j < NCC) { whv[j] = (_Float16)Wv[j]; return; }
    j -= NCC;
    if (j < NCC) { who[j] = (_Float16)Wo[j]; return; }
    j -= NCC;
    if (j < NFC) { wh1[j] = (_Float16)W1[j]; return; }
    j -= NFC;
    if (j < NFC) { wh2[j] = (_Float16)W2[j]; return; }
    j -= NFC;
    if (j < L_*QKM) {
        int c = j & 255, sel = (j >> 8) & 1, l = j >> 9;
        bqk[j] = sel ? bk[l*256 + c] : bq[l*256 + c];
    }
}

// ---------------- layernorm over C -> fp16 [b][ts][c] (layer-0 entry only) ----
template<bool HASPOS>
__global__ __launch_bounds__(256) void ln_t(const float* __restrict__ x,
                                            const float* __restrict__ gam,
                                            const float* __restrict__ bet,
                                            const float* __restrict__ pos,
                                            _Float16* __restrict__ s2,
                                            _Float16* __restrict__ qk) {
    __shared__ float redS[8][32];
    __shared__ float redQ[8][32];
    __shared__ _Float16 tiles[(HASPOS ? 2 : 1) * 32 * 256];
    _Float16* t0 = tiles;
    _Float16* t1 = tiles + 32 * 256;
    int tid = threadIdx.x;
    int nl = tid & 31, cg = tid >> 5;
    int gpos = blockIdx.x * 32;
    int b = gpos >> 13, nb = gpos & 8191;
    const float* xb = x + (size_t)b * C_ * NTS + nb + nl;
    float xv[32], pv[HASPOS ? 32 : 1];
    float sum = 0.f, sq = 0.f;
    #pragma unroll
    for (int j = 0; j < 32; ++j) {
        float v = xb[(size_t)(cg * 32 + j) * NTS];
        xv[j] = v; sum += v; sq += v * v;
    }
    if (HASPOS) {
        const float* pb = pos + (size_t)b * C_ * NTS + nb + nl;
        #pragma unroll
        for (int j = 0; j < 32; ++j) pv[j] = pb[(size_t)(cg * 32 + j) * NTS];
    }
    redS[cg][nl] = sum; redQ[cg][nl] = sq;
    __syncthreads();
    float s = 0.f, q = 0.f;
    #pragma unroll
    for (int g = 0; g < 8; ++g) { s += redS[g][nl]; q += redQ[g][nl]; }
    float mean = s * (1.0f / C_);
    float var  = q * (1.0f / C_) - mean * mean;
    float rstd = rsqrtf(var + 1e-5f);
    #pragma unroll
    for (int jj = 0; jj < 4; ++jj) {
        half8v h0, h1;
        #pragma unroll
        for (int j2 = 0; j2 < 8; ++j2) {
            int j = jj * 8 + j2;
            int c = cg * 32 + j;
            float y = (xv[j] - mean) * rstd * gam[c] + bet[c];
            h0[j2] = (_Float16)y;
            if (HASPOS) h1[j2] = (_Float16)(y + pv[j]);
        }
        int cs = (cg * 4 + jj) ^ nl;
        *(half8v*)(t0 + nl * 256 + cs * 8) = h0;
        if (HASPOS) *(half8v*)(t1 + nl * 256 + cs * 8) = h1;
    }
    __syncthreads();
    #pragma unroll
    for (int it = 0; it < 4; ++it) {
        int chunk = tid + it * 256;
        int row = chunk >> 5, ch = chunk & 31;
        int cs = ch ^ row;
        half8v v0 = *(half8v*)(t0 + row * 256 + cs * 8);
        *(half8v*)(s2 + (size_t)(gpos + row) * C_ + ch * 8) = v0;
        if (HASPOS) {
            half8v v1 = *(half8v*)(t1 + row * 256 + cs * 8);
            *(half8v*)(qk + (size_t)(gpos + row) * C_ + ch * 8) = v1;
        }
    }
}

// enc+pos -> fp16 [b][ts][c]  (layer-invariant; run ONCE)
__global__ __launch_bounds__(256) void addt_kernel(const float* __restrict__ a,
                                                   const float* __restrict__ p,
                                                   _Float16* __restrict__ o) {
    __shared__ _Float16 t0[32 * 256];
    int tid = threadIdx.x;
    int nl = tid & 31, cg = tid >> 5;
    int gpos = blockIdx.x * 32;
    int b = gpos >> 13, nb = gpos & 8191;
    const float* ab = a + (size_t)b * C_ * NTS + nb + nl;
    const float* pb = p + (size_t)b * C_ * NTS + nb + nl;
    float av[32], pv[32];
    #pragma unroll
    for (int j = 0; j < 32; ++j) av[j] = ab[(size_t)(cg * 32 + j) * NTS];
    #pragma unroll
    for (int j = 0; j < 32; ++j) pv[j] = pb[(size_t)(cg * 32 + j) * NTS];
    #pragma unroll
    for (int jj = 0; jj < 4; ++jj) {
        half8v h0;
        #pragma unroll
        for (int j2 = 0; j2 < 8; ++j2) {
            int j = jj * 8 + j2;
            h0[j2] = (_Float16)(av[j] + pv[j]);
        }
        int cs = (cg * 4 + jj) ^ nl;
        *(half8v*)(t0 + nl * 256 + cs * 8) = h0;
    }
    __syncthreads();
    #pragma unroll
    for (int it = 0; it < 4; ++it) {
        int chunk = tid + it * 256;
        int row = chunk >> 5, ch = chunk & 31;
        half8v v0 = *(half8v*)(t0 + row * 256 + (ch ^ row) * 8);
        *(half8v*)(o + (size_t)(gpos + row) * C_ + ch * 8) = v0;
    }
}

// ---------------- MFMA fp16 GEMM (128x128 tile, global_load_lds staging) -----
// MODE 1: dst f32 [b][M][N] = src + acc; MODE 2: relu -> fp16 [b][n][M].
template<int MODE>
__global__ __launch_bounds__(256) void gemm_mfma(const _Float16* __restrict__ W,
                                                 const float* __restrict__ bias,
                                                 const _Float16* __restrict__ X,
                                                 const float* __restrict__ src,
                                                 void* __restrict__ Yv, int M, int K) {
    __shared__ _Float16 As[128 * 32];
    __shared__ _Float16 Bs[128 * 32];
    int b  = blockIdx.z;
    int m0 = blockIdx.y * 128;
    int n0 = blockIdx.x * 128;
    const _Float16* Xb = X + (size_t)b * NTS * K;
    int tid = threadIdx.x;
    int wave = tid >> 6, lane = tid & 63;
    int wm = (wave >> 1) * 64, wn = (wave & 1) * 64;
    int r = lane & 15, g = lane >> 4;
    float4v acc[4][4];
    #pragma unroll
    for (int i = 0; i < 4; ++i)
        #pragma unroll
        for (int j = 0; j < 4; ++j) acc[i][j] = (float4v){0.f, 0.f, 0.f, 0.f};

    for (int k0 = 0; k0 < K; k0 += 32) {
        #pragma unroll
        for (int it = 0; it < 2; ++it) {
            int cbase = wave * 64 + it * 256;
            int rowbase = cbase >> 2;
            int row = rowbase + (lane >> 2);
            int ch = (lane & 3) ^ (row & 3);
            const _Float16* ga = W  + (size_t)(m0 + row) * K + k0 + ch * 8;
            const _Float16* gb = Xb + (size_t)(n0 + row) * K + k0 + ch * 8;
            __builtin_amdgcn_global_load_lds(
                (const __attribute__((address_space(1))) void*)ga,
                (__attribute__((address_space(3))) void*)(As + rowbase * 32), 16, 0, 0);
            __builtin_amdgcn_global_load_lds(
                (const __attribute__((address_space(1))) void*)gb,
                (__attribute__((address_space(3))) void*)(Bs + rowbase * 32), 16, 0, 0);
        }
        __syncthreads();
        half8v af[4], bf[4];
        #pragma unroll
        for (int mt = 0; mt < 4; ++mt) {
            int row = wm + mt * 16 + r;
            af[mt] = *(const half8v*)(As + row * 32 + ((g ^ (row & 3)) << 3));
        }
        #pragma unroll
        for (int nt = 0; nt < 4; ++nt) {
            int row = wn + nt * 16 + r;
            bf[nt] = *(const half8v*)(Bs + row * 32 + ((g ^ (row & 3)) << 3));
        }
        #pragma unroll
        for (int mt = 0; mt < 4; ++mt)
            #pragma unroll
            for (int nt = 0; nt < 4; ++nt)
                acc[mt][nt] = __builtin_amdgcn_mfma_f32_16x16x32_f16(af[mt], bf[nt], acc[mt][nt], 0, 0, 0);
        __syncthreads();
    }

    #pragma unroll
    for (int mt = 0; mt < 4; ++mt) {
        int m_base = m0 + wm + mt * 16 + g * 4;
        float bb[4];
        #pragma unroll
        for (int rr = 0; rr < 4; ++rr) bb[rr] = bias[m_base + rr];
        #pragma unroll
        for (int nt = 0; nt < 4; ++nt) {
            int n = n0 + wn + nt * 16 + r;
            if (MODE == 1) {
                float* Yd = (float*)Yv + (size_t)b * M * NTS;
                const float* Sd = src + (size_t)b * M * NTS;
                #pragma unroll
                for (int rr = 0; rr < 4; ++rr) {
                    size_t o = (size_t)(m_base + rr) * NTS + n;
                    Yd[o] = Sd[o] + acc[mt][nt][rr] + bb[rr];
                }
            } else {
                _Float16* Y = (_Float16*)Yv + (size_t)b * NTS * M;
                half4v hv;
                #pragma unroll
                for (int rr = 0; rr < 4; ++rr) {
                    float v = acc[mt][nt][rr] + bb[rr];
                    if (MODE == 2) v = fmaxf(v, 0.f);
                    hv[rr] = (_Float16)v;
                }
                *(half4v*)(Y + (size_t)n * M + m_base) = hv;
            }
        }
    }
}

// ---------------- fused QK+V projection (one dispatch) ----------------
// grid (64, 6, B): y<4 -> QK part (M=512), y>=4 -> V part (M=256). MODE 0 store.
__global__ __launch_bounds__(256) void gemm_qkv(
        const _Float16* __restrict__ Wqk, const float* __restrict__ bqk,
        const _Float16* __restrict__ Xqk, _Float16* __restrict__ Yqk,
        const _Float16* __restrict__ Wv, const float* __restrict__ bv,
        const _Float16* __restrict__ Xv, _Float16* __restrict__ Yv) {
    __shared__ _Float16 As[128 * 32];
    __shared__ _Float16 Bs[128 * 32];
    const _Float16 *W, *X; const float* bias; _Float16* Y; int M, m0;
    if (blockIdx.y < 4) { W = Wqk; bias = bqk; X = Xqk; Y = Yqk; M = QKM; m0 = blockIdx.y * 128; }
    else                { W = Wv;  bias = bv;  X = Xv;  Y = Yv;  M = C_;  m0 = (blockIdx.y - 4) * 128; }
    const int K = C_;
    int b  = blockIdx.z;
    int n0 = blockIdx.x * 128;
    const _Float16* Xb = X + (size_t)b * NTS * K;
    int tid = threadIdx.x;
    int wave = tid >> 6, lane = tid & 63;
    int wm = (wave >> 1) * 64, wn = (wave & 1) * 64;
    int r = lane & 15, g = lane >> 4;
    float4v acc[4][4];
    #pragma unroll
    for (int i = 0; i < 4; ++i)
        #pragma unroll
        for (int j = 0; j < 4; ++j) acc[i][j] = (float4v){0.f, 0.f, 0.f, 0.f};

    for (int k0 = 0; k0 < K; k0 += 32) {
        #pragma unroll
        for (int it = 0; it < 2; ++it) {
            int cbase = wave * 64 + it * 256;
            int rowbase = cbase >> 2;
            int row = rowbase + (lane >> 2);
            int ch = (lane & 3) ^ (row & 3);
            const _Float16* ga = W  + (size_t)(m0 + row) * K + k0 + ch * 8;
            const _Float16* gb = Xb + (size_t)(n0 + row) * K + k0 + ch * 8;
            __builtin_amdgcn_global_load_lds(
                (const __attribute__((address_space(1))) void*)ga,
                (__attribute__((address_space(3))) void*)(As + rowbase * 32), 16, 0, 0);
            __builtin_amdgcn_global_load_lds(
                (const __attribute__((address_space(1))) void*)gb,
                (__attribute__((address_space(3))) void*)(Bs + rowbase * 32), 16, 0, 0);
        }
        __syncthreads();
        half8v af[4], bf[4];
        #pragma unroll
        for (int mt = 0; mt < 4; ++mt) {
            int row = wm + mt * 16 + r;
            af[mt] = *(const half8v*)(As + row * 32 + ((g ^ (row & 3)) << 3));
        }
        #pragma unroll
        for (int nt = 0; nt < 4; ++nt) {
            int row = wn + nt * 16 + r;
            bf[nt] = *(const half8v*)(Bs + row * 32 + ((g ^ (row & 3)) << 3));
        }
        #pragma unroll
        for (int mt = 0; mt < 4; ++mt)
            #pragma unroll
            for (int nt = 0; nt < 4; ++nt)
                acc[mt][nt] = __builtin_amdgcn_mfma_f32_16x16x32_f16(af[mt], bf[nt], acc[mt][nt], 0, 0, 0);
        __syncthreads();
    }
    #pragma unroll
    for (int mt = 0; mt < 4; ++mt) {
        int m_base = m0 + wm + mt * 16 + g * 4;
        float bb[4];
        #pragma unroll
        for (int rr = 0; rr < 4; ++rr) bb[rr] = bias[m_base + rr];
        #pragma unroll
        for (int nt = 0; nt < 4; ++nt) {
            int n = n0 + wn + nt * 16 + r;
            half4v hv;
            #pragma unroll
            for (int rr = 0; rr < 4; ++rr)
                hv[rr] = (_Float16)(acc[mt][nt][rr] + bb[rr]);
            *(half4v*)(Y + ((size_t)b * NTS + n) * M + m_base) = hv;
        }
    }
}

// ---------------- residual GEMM with fused LayerNorm epilogue ----------------
// Block = full channel column: M=256 x N=64 tile. dec = src + W.X + bias (f32),
// then LN over channels in-block -> s2 fp16 [b][n][c] (+ optional qk = s2+pos).
// Wave w owns m in [64w, 64w+64); 4 n-frags of 16.
template<bool POS>
__global__ __launch_bounds__(256) void gemm_res_ln(
        const _Float16* __restrict__ W, const float* __restrict__ bias,
        const _Float16* __restrict__ X, const float* __restrict__ src,
        float* __restrict__ dec, const float* __restrict__ gam,
        const float* __restrict__ bet, const float* __restrict__ pos,
        _Float16* __restrict__ s2, _Float16* __restrict__ qk, int K) {
    __shared__ _Float16 As[256 * 32];   // 16 KB
    __shared__ _Float16 Bs[64 * 32];    // 4 KB
    __shared__ float sumS[4][64], sumQ[4][64];
    __shared__ float meanL[64], rstdL[64];
    int b  = blockIdx.z;
    int n0 = blockIdx.x * 64;
    const _Float16* Xb = X + (size_t)b * NTS * K;
    int tid = threadIdx.x;
    int wave = tid >> 6, lane = tid & 63;
    int wm = wave * 64;
    int r = lane & 15, g = lane >> 4;
    float4v acc[4][4];
    #pragma unroll
    for (int i = 0; i < 4; ++i)
        #pragma unroll
        for (int j = 0; j < 4; ++j) acc[i][j] = (float4v){0.f, 0.f, 0.f, 0.f};

    for (int k0 = 0; k0 < K; k0 += 32) {
        // A-tile: 256 rows x 32 k = 1024 chunks (4 rounds)
        #pragma unroll
        for (int it = 0; it < 4; ++it) {
            int cbase = wave * 64 + it * 256;
            int rowbase = cbase >> 2;
            int row = rowbase + (lane >> 2);
            int ch = (lane & 3) ^ (row & 3);
            const _Float16* ga = W + (size_t)row * K + k0 + ch * 8;
            __builtin_amdgcn_global_load_lds(
                (const __attribute__((address_space(1))) void*)ga,
                (__attribute__((address_space(3))) void*)(As + rowbase * 32), 16, 0, 0);
        }
        // B-tile: 64 rows x 32 k = 256 chunks (1 round)
        {
            int cbase = wave * 64;
            int rowbase = cbase >> 2;
            int row = rowbase + (lane >> 2);
            int ch = (lane & 3) ^ (row & 3);
            const _Float16* gb = Xb + (size_t)(n0 + row) * K + k0 + ch * 8;
            __builtin_amdgcn_global_load_lds(
                (const __attribute__((address_space(1))) void*)gb,
                (__attribute__((address_space(3))) void*)(Bs + rowbase * 32), 16, 0, 0);
        }
        __syncthreads();
        half8v af[4], bf[4];
        #pragma unroll
        for (int mt = 0; mt < 4; ++mt) {
            int row = wm + mt * 16 + r;
            af[mt] = *(const half8v*)(As + row * 32 + ((g ^ (row & 3)) << 3));
        }
        #pragma unroll
        for (int nt = 0; nt < 4; ++nt) {
            int row = nt * 16 + r;
            bf[nt] = *(const half8v*)(Bs + row * 32 + ((g ^ (row & 3)) << 3));
        }
        #pragma unroll
        for (int mt = 0; mt < 4; ++mt)
            #pragma unroll
            for (int nt = 0; nt < 4; ++nt)
                acc[mt][nt] = __builtin_amdgcn_mfma_f32_16x16x32_f16(af[mt], bf[nt], acc[mt][nt], 0, 0, 0);
        __syncthreads();
    }

    const float* Sd = src + (size_t)b * C_ * NTS;
    float* Dd = dec + (size_t)b * C_ * NTS;
    // fold src + bias into acc; store dec
    #pragma unroll
    for (int mt = 0; mt < 4; ++mt) {
        int mb = wm + mt * 16 + g * 4;
        float bb[4];
        #pragma unroll
        for (int rr = 0; rr < 4; ++rr) bb[rr] = bias[mb + rr];
        #pragma unroll
        for (int nt = 0; nt < 4; ++nt) {
            int n = n0 + nt * 16 + r;
            #pragma unroll
            for (int rr = 0; rr < 4; ++rr) {
                size_t o = (size_t)(mb + rr) * NTS + n;
                float v = Sd[o] + acc[mt][nt][rr] + bb[rr];
                acc[mt][nt][rr] = v;
                Dd[o] = v;
            }
        }
    }
    // LN stats: per-n sums over this wave's 64 m, then cross-wave
    #pragma unroll
    for (int nt = 0; nt < 4; ++nt) {
        float ps = 0.f, pq = 0.f;
        #pragma unroll
        for (int mt = 0; mt < 4; ++mt)
            #pragma unroll
            for (int rr = 0; rr < 4; ++rr) {
                float v = acc[mt][nt][rr];
                ps += v; pq += v * v;
            }
        ps += __shfl_xor(ps, 16, 64); pq += __shfl_xor(pq, 16, 64);
        ps += __shfl_xor(ps, 32, 64); pq += __shfl_xor(pq, 32, 64);
        if (g == 0) { sumS[wave][nt * 16 + r] = ps; sumQ[wave][nt * 16 + r] = pq; }
    }
    __syncthreads();
    if (tid < 64) {
        float s = sumS[0][tid] + sumS[1][tid] + sumS[2][tid] + sumS[3][tid];
        float q = sumQ[0][tid] + sumQ[1][tid] + sumQ[2][tid] + sumQ[3][tid];
        float mean = s * (1.0f / C_);
        float var  = q * (1.0f / C_) - mean * mean;
        meanL[tid] = mean;
        rstdL[tid] = rsqrtf(var + 1e-5f);
    }
    __syncthreads();
    // normalized fp16 outputs
    const float* Pb = POS ? pos + (size_t)b * C_ * NTS : nullptr;
    #pragma unroll
    for (int mt = 0; mt < 4; ++mt) {
        int mb = wm + mt * 16 + g * 4;
        float gm[4], be[4];
        #pragma unroll
        for (int rr = 0; rr < 4; ++rr) { gm[rr] = gam[mb + rr]; be[rr] = bet[mb + rr]; }
        #pragma unroll
        for (int nt = 0; nt < 4; ++nt) {
            int n = n0 + nt * 16 + r;
            float mean = meanL[nt * 16 + r], rstd = rstdL[nt * 16 + r];
            half4v hv, hq;
            #pragma unroll
            for (int rr = 0; rr < 4; ++rr) {
                float y = (acc[mt][nt][rr] - mean) * rstd * gm[rr] + be[rr];
                hv[rr] = (_Float16)y;
                if (POS) hq[rr] = (_Float16)(y + Pb[(size_t)(mb + rr) * NTS + n]);
            }
            *(half4v*)(s2 + ((size_t)b * NTS + n) * C_ + mb) = hv;
            if (POS) *(half4v*)(qk + ((size_t)b * NTS + n) * C_ + mb) = hq;
        }
    }
}

// ---------------- gate bits + counts precompute ----------------
__global__ __launch_bounds__(256) void gate_kernel(const float* __restrict__ coord,
                                                   const int* __restrict__ mask,
                                                   unsigned long long* __restrict__ gwb,
                                                   int* __restrict__ ucb,
                                                   unsigned long long* __restrict__ umb) {
    int wid  = blockIdx.x * 4 + (threadIdx.x >> 6);   // bt*512 + q
    int lane = threadIdx.x & 63;
    int q  = wid & 511;
    int bt = wid >> 9;
    const float* cb = coord + (size_t)bt * S_ * 3;
    const int* mrow = mask + (size_t)bt * S_;
    float cq0 = cb[q*3+0], cq1 = cb[q*3+1], cq2 = cb[q*3+2];
    int ucnt = 0;
    for (int i = 0; i < 8; ++i) {
        int k = i * 64 + lane;
        float dx = cq0 - cb[k*3+0];
        float dy = cq1 - cb[k*3+1];
        float dz = cq2 - cb[k*3+2];
        bool near = (dx*dx + dy*dy + dz*dz) < 625.0f;
        bool um = (mrow[k] == 0);
        unsigned long long gm = __ballot(near && um);
        unsigned long long un = __ballot(um);
        if (lane == 0) {
            gwb[(size_t)wid*8 + i] = gm;
            ucnt += __popcll(un);
            if (q == 0) umb[bt*8 + i] = un;
        }
    }
    if (lane == 0) ucb[wid] = ucnt;
}

// ---------------- sparse distance-gated attention ----------------
__global__ __launch_bounds__(256) void attn_kernel(
        const _Float16* __restrict__ qk, const _Float16* __restrict__ v,
        const unsigned long long* __restrict__ gwb, const int* __restrict__ ucb,
        const unsigned long long* __restrict__ umb, _Float16* __restrict__ out) {
    __shared__ _Float16 KV[S_ * 72];    // 72 KB: row s = [K 32 | V 32 | pad 8]
    __shared__ float Upart[8][32];
    __shared__ float Ufin[HD_];
    int bid  = blockIdx.x;
    int half = bid & 1;
    int bht  = bid >> 1;
    int t = bht & (T_-1), h = (bht >> 4) & (H_-1), b = bht >> 7;
    int tid = threadIdx.x;
    int bt = b * T_ + t;
    const _Float16* kg = qk + ((size_t)bt * S_) * QKM + 256 + h * HD_;
    const _Float16* vg = v  + ((size_t)bt * S_) * C_  + h * HD_;

    #pragma unroll
    for (int it = 0; it < 8; ++it) {
        int c = tid + it * 256;
        int s = c >> 2, ch = c & 3;
        *(half8v*)(KV + s * 72 + ch * 8)      = *(const half8v*)(kg + (size_t)s * QKM + ch * 8);
        *(half8v*)(KV + s * 72 + 32 + ch * 8) = *(const half8v*)(vg + (size_t)s * C_ + ch * 8);
    }

    int qi = half * 256 + tid;
    h8u qa[4];
    {
        const half8v* qp = (const half8v*)(qk + ((size_t)bt * S_ + qi) * QKM + h * HD_);
        #pragma unroll
        for (int i = 0; i < 4; ++i) qa[i].v = qp[i];
    }
    __syncthreads();

    {
        int d = tid & 31, grp = tid >> 5;
        unsigned long long um = umb[bt*8 + grp];
        float s = 0.f;
        for (int kk = 0; kk < 64; ++kk)
            if ((um >> kk) & 1) s += (float)KV[(grp*64 + kk) * 72 + 32 + d];
        Upart[grp][d] = s;
    }
    __syncthreads();
    if (tid < HD_) {
        float s = 0.f;
        #pragma unroll
        for (int gp = 0; gp < 8; ++gp) s += Upart[gp][tid];
        Ufin[tid] = s;
    }
    __syncthreads();

    const unsigned long long* gw8 = gwb + ((size_t)bt * S_ + qi) * 8;
    float O[HD_];
    #pragma unroll
    for (int d = 0; d < HD_; ++d) O[d] = 0.f;
    float l = (float)ucb[(size_t)bt * S_ + qi];

    for (int w = 0; w < 8; ++w) {
        unsigned long long gw = gw8[w];
        while (gw) {
            int j = __builtin_ctzll(gw);
            gw &= gw - 1;
            const _Float16* row = KV + (w * 64 + j) * 72;
            h8u k0, k1, k2, k3;
            k0.v = *(const half8v*)(row);
            k1.v = *(const half8v*)(row + 8);
            k2.v = *(const half8v*)(row + 16);
            k3.v = *(const half8v*)(row + 24);
            float s = 0.f;
            #pragma unroll
            for (int i = 0; i < 4; ++i) {
                s = __builtin_amdgcn_fdot2(k0.h[i], qa[0].h[i], s, false);
                s = __builtin_amdgcn_fdot2(k1.h[i], qa[1].h[i], s, false);
                s = __builtin_amdgcn_fdot2(k2.h[i], qa[2].h[i], s, false);
                s = __builtin_amdgcn_fdot2(k3.h[i], qa[3].h[i], s, false);
            }
            s *= 0.17677669529663687f;
            float e = __expf(fminf(s, 80.f));
            float em1 = e - 1.f;
            l += em1;
            half8v v0 = *(const half8v*)(row + 32);
            half8v v1 = *(const half8v*)(row + 40);
            half8v v2 = *(const half8v*)(row + 48);
            half8v v3 = *(const half8v*)(row + 56);
            #pragma unroll
            for (int d = 0; d < 8; ++d) {
                O[d]      = fmaf((float)v0[d], em1, O[d]);
                O[d + 8]  = fmaf((float)v1[d], em1, O[d + 8]);
                O[d + 16] = fmaf((float)v2[d], em1, O[d + 16]);
                O[d + 24] = fmaf((float)v3[d], em1, O[d + 24]);
            }
        }
    }
    float invl = 1.0f / l;
    _Float16* orow = out + ((size_t)bt * S_ + qi) * C_ + h * HD_;
    #pragma unroll
    for (int c0 = 0; c0 < 4; ++c0) {
        half8v hv;
        #pragma unroll
        for (int j = 0; j < 8; ++j)
            hv[j] = (_Float16)((O[c0*8+j] + Ufin[c0*8+j]) * invl);
        *(half8v*)(orow + c0 * 8) = hv;
    }
}

// ---------------- driver ----------------
extern "C" void kernel_launch(void* const* d_in, const int* in_sizes, int n_in,
                              void* d_out, int out_size, void* d_ws, size_t ws_size,
                              hipStream_t stream) {
    const float* decoder = (const float*)d_in[0];
    const float* encoder = (const float*)d_in[1];
    const float* pos     = (const float*)d_in[2];
    const float* coord   = (const float*)d_in[3];
    const int*   mask    = (const int*)d_in[4];
    const float* Wq = (const float*)d_in[5],  *bq = (const float*)d_in[6];
    const float* Wk = (const float*)d_in[7],  *bk = (const float*)d_in[8];
    const float* Wv = (const float*)d_in[9],  *bv = (const float*)d_in[10];
    const float* Wo = (const float*)d_in[11], *bo = (const float*)d_in[12];
    const float* W1 = (const float*)d_in[13], *b1 = (const float*)d_in[14];
    const float* W2 = (const float*)d_in[15], *b2 = (const float*)d_in[16];
    const float* ln_g = (const float*)d_in[17], *ln_b = (const float*)d_in[18];

    float* dec = (float*)d_out;

    size_t actsz = (size_t)B_ * NTS * C_;          // 4.19M halves (8.4 MB)
    _Float16* qkT  = (_Float16*)d_ws;              // 1
    _Float16* qkT2 = qkT + actsz;                  // 2 (fused Q|K output)
    _Float16* vT   = qkT2 + 2*actsz;               // 1
    _Float16* s2T  = vT + actsz;                   // 1 (LN outputs)
    _Float16* aT   = s2T + actsz;                  // 1 (attn output)
    _Float16* encT = aT + actsz;                   // 1 (enc+pos, layer-invariant)
    _Float16* hT   = encT + actsz;                 // 4 (FFN hidden, dedicated)
    _Float16* whqk = hT + 4*actsz;
    _Float16* whv  = whqk + (size_t)L_*QKM*C_;
    _Float16* who  = whv + (size_t)L_*C_*C_;
    _Float16* wh1  = who + (size_t)L_*C_*C_;
    _Float16* wh2  = wh1 + (size_t)L_*DFF_*C_;
    float* bqk = (float*)(wh2 + (size_t)L_*C_*DFF_);
    unsigned long long* gwb = (unsigned long long*)(bqk + L_*QKM);
    int* ucb = (int*)(gwb + (size_t)B_*T_*S_*8);
    unsigned long long* umb = (unsigned long long*)(ucb + (size_t)B_*T_*S_);

    dim3 gGridQKV(NTS/128, 6, B_);        // fused QK(4) + V(2)
    dim3 gGridC(NTS/128, C_/128, B_);     // (64, 2, 2)
    dim3 gGridF(NTS/128, DFF_/128, B_);   // (64, 8, 2)
    dim3 gGridRL(NTS/64, 1, B_);          // (128, 1, 2) res+LN fused
    dim3 lnGrid(B_ * NTS / 32);
    dim3 attnGrid(B_ * H_ * T_ * 2);
    dim3 gateGrid(B_ * T_ * S_ / 4);
    dim3 prepGrid(6148);

    gate_kernel<<<gateGrid, 256, 0, stream>>>(coord, mask, gwb, ucb, umb);
    prep_kernel<<<prepGrid, 256, 0, stream>>>(Wq, Wk, Wv, Wo, W1, W2, bq, bk,
                                              whqk, whv, who, wh1, wh2, bqk);
    addt_kernel<<<lnGrid, 256, 0, stream>>>(encoder, pos, encT);   // layer-invariant

    for (int l = 0; l < L_; ++l) {
        const _Float16* whqk_l = whqk + (size_t)l*QKM*C_; const float* bqk_l = bqk + l*QKM;
        const _Float16* whv_l = whv + (size_t)l*C_*C_;  const float* bv_l = bv + l*C_;
        const _Float16* who_l = who + (size_t)l*C_*C_;  const float* bo_l = bo + l*C_;
        const _Float16* wh1_l = wh1 + (size_t)l*DFF_*C_; const float* b1_l = b1 + l*DFF_;
        const _Float16* wh2_l = wh2 + (size_t)l*C_*DFF_; const float* b2_l = b2 + l*C_;
        const float* g0 = ln_g + ((size_t)l*3 + 0)*C_; const float* e0 = ln_b + ((size_t)l*3 + 0)*C_;
        const float* g1 = ln_g + ((size_t)l*3 + 1)*C_; const float* e1 = ln_b + ((size_t)l*3 + 1)*C_;
        const float* g2 = ln_g + ((size_t)l*3 + 2)*C_; const float* e2 = ln_b + ((size_t)l*3 + 2)*C_;

        // ---- block A: qk = LN0(x)+pos, v-input = LN0(x)
        if (l == 0)   // layers >0 get s2T/qkT from the previous fused W2 epilogue
            ln_t<true><<<lnGrid, 256, 0, stream>>>(decoder, g0, e0, pos, s2T, qkT);
        gemm_qkv<<<gGridQKV, 256, 0, stream>>>(whqk_l, bqk_l, qkT, qkT2,
                                               whv_l, bv_l, s2T, vT);
        attn_kernel<<<attnGrid, 256, 0, stream>>>(qkT2, vT, gwb, ucb, umb, aT);
        // O-proj + residual, fused LN1 -> s2T
        gemm_res_ln<false><<<gGridRL, 256, 0, stream>>>(who_l, bo_l, aT,
                (l == 0) ? decoder : dec, dec, g1, e1, nullptr, s2T, nullptr, C_);

        // ---- block B: qk = enc+pos (precomputed encT), v-input = LN1(dec)=s2T
        gemm_qkv<<<gGridQKV, 256, 0, stream>>>(whqk_l, bqk_l, encT, qkT2,
                                               whv_l, bv_l, s2T, vT);
        attn_kernel<<<attnGrid, 256, 0, stream>>>(qkT2, vT, gwb, ucb, umb, aT);
        // O-proj + residual, fused LN2 -> s2T (FFN input)
        gemm_res_ln<false><<<gGridRL, 256, 0, stream>>>(who_l, bo_l, aT,
                dec, dec, g2, e2, nullptr, s2T, nullptr, C_);

        // ---- FFN
        gemm_mfma<2><<<gGridF, 256, 0, stream>>>(wh1_l, b1_l, s2T, nullptr, hT, DFF_, C_);
        if (l + 1 < L_) {
            const float* g0n = ln_g + ((size_t)(l+1)*3 + 0)*C_;
            const float* e0n = ln_b + ((size_t)(l+1)*3 + 0)*C_;
            // W2 + residual, fused LN0(next layer) -> s2T and qkT (+pos)
            gemm_res_ln<true><<<gGridRL, 256, 0, stream>>>(wh2_l, b2_l, hT,
                    dec, dec, g0n, e0n, pos, s2T, qkT, DFF_);
        } else {
            gemm_mfma<1><<<gGridC, 256, 0, stream>>>(wh2_l, b2_l, hT, dec, dec, C_, DFF_);
        }
    }
}

// Round 8
// 505.364 us; speedup vs baseline: 1.3849x; 1.0586x over previous
//
#include <hip/hip_runtime.h>
#include <math.h>

#define L_ 2
#define B_ 2
#define C_ 256
#define H_ 8
#define HD_ 32
#define T_ 16
#define S_ 512
#define DFF_ 1024
#define NTS (T_*S_)                 // 8192
#define NELEM ((size_t)B_*C_*T_*S_) // 4194304
#define QKM 512                     // fused Q|K output channels

typedef _Float16 half8v __attribute__((ext_vector_type(8)));
typedef _Float16 half4v __attribute__((ext_vector_type(4)));
typedef _Float16 half2v __attribute__((ext_vector_type(2)));
typedef float   float4v __attribute__((ext_vector_type(4)));

union h8u { half8v v; half2v h[4]; };

// ---------------- fused weight prep ----------------
__global__ void prep_kernel(const float* __restrict__ Wq, const float* __restrict__ Wk,
                            const float* __restrict__ Wv, const float* __restrict__ Wo,
                            const float* __restrict__ W1, const float* __restrict__ W2,
                            const float* __restrict__ bq, const float* __restrict__ bk,
                            _Float16* __restrict__ whqk, _Float16* __restrict__ whv,
                            _Float16* __restrict__ who, _Float16* __restrict__ wh1,
                            _Float16* __restrict__ wh2, float* __restrict__ bqk) {
    int i = blockIdx.x * 256 + threadIdx.x;
    const int NQK = L_*QKM*C_;      // 262144
    const int NCC = L_*C_*C_;       // 131072
    const int NFC = L_*DFF_*C_;     // 524288
    if (i < NQK) {
        int k = i & 255, m = (i >> 8) & 511, l = i >> 17;
        float v = (m < 256) ? Wq[((size_t)l*256 + m)*256 + k]
                            : Wk[((size_t)l*256 + (m-256))*256 + k];
        whqk[i] = (_Float16)v;
        return;
    }
    int j = i - NQK;
    if (j < NCC) { whv[j] = (_Float16)Wv[j]; return; }
    j -= NCC;
    if (j < NCC) { who[j] = (_Float16)Wo[j]; return; }
    j -= NCC;
    if (j < NFC) { wh1[j] = (_Float16)W1[j]; return; }
    j -= NFC;
    if (j < NFC) { wh2[j] = (_Float16)W2[j]; return; }
    j -= NFC;
    if (j < L_*QKM) {
        int c = j & 255, sel = (j >> 8) & 1, l = j >> 9;
        bqk[j] = sel ? bk[l*256 + c] : bq[l*256 + c];
    }
}

// ---------------- layernorm over C -> fp16 [b][ts][c] (layer-0 entry only) ----
template<bool HASPOS>
__global__ __launch_bounds__(256) void ln_t(const float* __restrict__ x,
                                            const float* __restrict__ gam,
                                            const float* __restrict__ bet,
                                            const float* __restrict__ pos,
                                            _Float16* __restrict__ s2,
                                            _Float16* __restrict__ qk) {
    __shared__ float redS[8][32];
    __shared__ float redQ[8][32];
    __shared__ _Float16 tiles[(HASPOS ? 2 : 1) * 32 * 256];
    _Float16* t0 = tiles;
    _Float16* t1 = tiles + 32 * 256;
    int tid = threadIdx.x;
    int nl = tid & 31, cg = tid >> 5;
    int gpos = blockIdx.x * 32;
    int b = gpos >> 13, nb = gpos & 8191;
    const float* xb = x + (size_t)b * C_ * NTS + nb + nl;
    float xv[32], pv[HASPOS ? 32 : 1];
    float sum = 0.f, sq = 0.f;
    #pragma unroll
    for (int j = 0; j < 32; ++j) {
        float v = xb[(size_t)(cg * 32 + j) * NTS];
        xv[j] = v; sum += v; sq += v * v;
    }
    if (HASPOS) {
        const float* pb = pos + (size_t)b * C_ * NTS + nb + nl;
        #pragma unroll
        for (int j = 0; j < 32; ++j) pv[j] = pb[(size_t)(cg * 32 + j) * NTS];
    }
    redS[cg][nl] = sum; redQ[cg][nl] = sq;
    __syncthreads();
    float s = 0.f, q = 0.f;
    #pragma unroll
    for (int g = 0; g < 8; ++g) { s += redS[g][nl]; q += redQ[g][nl]; }
    float mean = s * (1.0f / C_);
    float var  = q * (1.0f / C_) - mean * mean;
    float rstd = rsqrtf(var + 1e-5f);
    #pragma unroll
    for (int jj = 0; jj < 4; ++jj) {
        half8v h0, h1;
        #pragma unroll
        for (int j2 = 0; j2 < 8; ++j2) {
            int j = jj * 8 + j2;
            int c = cg * 32 + j;
            float y = (xv[j] - mean) * rstd * gam[c] + bet[c];
            h0[j2] = (_Float16)y;
            if (HASPOS) h1[j2] = (_Float16)(y + pv[j]);
        }
        int cs = (cg * 4 + jj) ^ nl;
        *(half8v*)(t0 + nl * 256 + cs * 8) = h0;
        if (HASPOS) *(half8v*)(t1 + nl * 256 + cs * 8) = h1;
    }
    __syncthreads();
    #pragma unroll
    for (int it = 0; it < 4; ++it) {
        int chunk = tid + it * 256;
        int row = chunk >> 5, ch = chunk & 31;
        int cs = ch ^ row;
        half8v v0 = *(half8v*)(t0 + row * 256 + cs * 8);
        *(half8v*)(s2 + (size_t)(gpos + row) * C_ + ch * 8) = v0;
        if (HASPOS) {
            half8v v1 = *(half8v*)(t1 + row * 256 + cs * 8);
            *(half8v*)(qk + (size_t)(gpos + row) * C_ + ch * 8) = v1;
        }
    }
}

// enc+pos -> fp16 [b][ts][c]  (layer-invariant; run ONCE)
__global__ __launch_bounds__(256) void addt_kernel(const float* __restrict__ a,
                                                   const float* __restrict__ p,
                                                   _Float16* __restrict__ o) {
    __shared__ _Float16 t0[32 * 256];
    int tid = threadIdx.x;
    int nl = tid & 31, cg = tid >> 5;
    int gpos = blockIdx.x * 32;
    int b = gpos >> 13, nb = gpos & 8191;
    const float* ab = a + (size_t)b * C_ * NTS + nb + nl;
    const float* pb = p + (size_t)b * C_ * NTS + nb + nl;
    float av[32], pv[32];
    #pragma unroll
    for (int j = 0; j < 32; ++j) av[j] = ab[(size_t)(cg * 32 + j) * NTS];
    #pragma unroll
    for (int j = 0; j < 32; ++j) pv[j] = pb[(size_t)(cg * 32 + j) * NTS];
    #pragma unroll
    for (int jj = 0; jj < 4; ++jj) {
        half8v h0;
        #pragma unroll
        for (int j2 = 0; j2 < 8; ++j2) {
            int j = jj * 8 + j2;
            h0[j2] = (_Float16)(av[j] + pv[j]);
        }
        int cs = (cg * 4 + jj) ^ nl;
        *(half8v*)(t0 + nl * 256 + cs * 8) = h0;
    }
    __syncthreads();
    #pragma unroll
    for (int it = 0; it < 4; ++it) {
        int chunk = tid + it * 256;
        int row = chunk >> 5, ch = chunk & 31;
        half8v v0 = *(half8v*)(t0 + row * 256 + (ch ^ row) * 8);
        *(half8v*)(o + (size_t)(gpos + row) * C_ + ch * 8) = v0;
    }
}

// ---------------- MFMA fp16 GEMM (128x128 tile, global_load_lds staging) -----
// MODE 1: dst f32 [b][M][N] = src + acc; MODE 2: relu -> fp16 [b][n][M].
template<int MODE>
__global__ __launch_bounds__(256) void gemm_mfma(const _Float16* __restrict__ W,
                                                 const float* __restrict__ bias,
                                                 const _Float16* __restrict__ X,
                                                 const float* __restrict__ src,
                                                 void* __restrict__ Yv, int M, int K) {
    __shared__ _Float16 As[128 * 32];
    __shared__ _Float16 Bs[128 * 32];
    int b  = blockIdx.z;
    int m0 = blockIdx.y * 128;
    int n0 = blockIdx.x * 128;
    const _Float16* Xb = X + (size_t)b * NTS * K;
    int tid = threadIdx.x;
    int wave = tid >> 6, lane = tid & 63;
    int wm = (wave >> 1) * 64, wn = (wave & 1) * 64;
    int r = lane & 15, g = lane >> 4;
    float4v acc[4][4];
    #pragma unroll
    for (int i = 0; i < 4; ++i)
        #pragma unroll
        for (int j = 0; j < 4; ++j) acc[i][j] = (float4v){0.f, 0.f, 0.f, 0.f};

    for (int k0 = 0; k0 < K; k0 += 32) {
        #pragma unroll
        for (int it = 0; it < 2; ++it) {
            int cbase = wave * 64 + it * 256;
            int rowbase = cbase >> 2;
            int row = rowbase + (lane >> 2);
            int ch = (lane & 3) ^ (row & 3);
            const _Float16* ga = W  + (size_t)(m0 + row) * K + k0 + ch * 8;
            const _Float16* gb = Xb + (size_t)(n0 + row) * K + k0 + ch * 8;
            __builtin_amdgcn_global_load_lds(
                (const __attribute__((address_space(1))) void*)ga,
                (__attribute__((address_space(3))) void*)(As + rowbase * 32), 16, 0, 0);
            __builtin_amdgcn_global_load_lds(
                (const __attribute__((address_space(1))) void*)gb,
                (__attribute__((address_space(3))) void*)(Bs + rowbase * 32), 16, 0, 0);
        }
        __syncthreads();
        half8v af[4], bf[4];
        #pragma unroll
        for (int mt = 0; mt < 4; ++mt) {
            int row = wm + mt * 16 + r;
            af[mt] = *(const half8v*)(As + row * 32 + ((g ^ (row & 3)) << 3));
        }
        #pragma unroll
        for (int nt = 0; nt < 4; ++nt) {
            int row = wn + nt * 16 + r;
            bf[nt] = *(const half8v*)(Bs + row * 32 + ((g ^ (row & 3)) << 3));
        }
        #pragma unroll
        for (int mt = 0; mt < 4; ++mt)
            #pragma unroll
            for (int nt = 0; nt < 4; ++nt)
                acc[mt][nt] = __builtin_amdgcn_mfma_f32_16x16x32_f16(af[mt], bf[nt], acc[mt][nt], 0, 0, 0);
        __syncthreads();
    }

    #pragma unroll
    for (int mt = 0; mt < 4; ++mt) {
        int m_base = m0 + wm + mt * 16 + g * 4;
        float bb[4];
        #pragma unroll
        for (int rr = 0; rr < 4; ++rr) bb[rr] = bias[m_base + rr];
        #pragma unroll
        for (int nt = 0; nt < 4; ++nt) {
            int n = n0 + wn + nt * 16 + r;
            if (MODE == 1) {
                float* Yd = (float*)Yv + (size_t)b * M * NTS;
                const float* Sd = src + (size_t)b * M * NTS;
                #pragma unroll
                for (int rr = 0; rr < 4; ++rr) {
                    size_t o = (size_t)(m_base + rr) * NTS + n;
                    Yd[o] = Sd[o] + acc[mt][nt][rr] + bb[rr];
                }
            } else {
                _Float16* Y = (_Float16*)Yv + (size_t)b * NTS * M;
                half4v hv;
                #pragma unroll
                for (int rr = 0; rr < 4; ++rr) {
                    float v = acc[mt][nt][rr] + bb[rr];
                    if (MODE == 2) v = fmaxf(v, 0.f);
                    hv[rr] = (_Float16)v;
                }
                *(half4v*)(Y + (size_t)n * M + m_base) = hv;
            }
        }
    }
}

// ---------------- fused QK+V projection (one dispatch) ----------------
__global__ __launch_bounds__(256) void gemm_qkv(
        const _Float16* __restrict__ Wqk, const float* __restrict__ bqk,
        const _Float16* __restrict__ Xqk, _Float16* __restrict__ Yqk,
        const _Float16* __restrict__ Wv, const float* __restrict__ bv,
        const _Float16* __restrict__ Xv, _Float16* __restrict__ Yv) {
    __shared__ _Float16 As[128 * 32];
    __shared__ _Float16 Bs[128 * 32];
    const _Float16 *W, *X; const float* bias; _Float16* Y; int M, m0;
    if (blockIdx.y < 4) { W = Wqk; bias = bqk; X = Xqk; Y = Yqk; M = QKM; m0 = blockIdx.y * 128; }
    else                { W = Wv;  bias = bv;  X = Xv;  Y = Yv;  M = C_;  m0 = (blockIdx.y - 4) * 128; }
    const int K = C_;
    int b  = blockIdx.z;
    int n0 = blockIdx.x * 128;
    const _Float16* Xb = X + (size_t)b * NTS * K;
    int tid = threadIdx.x;
    int wave = tid >> 6, lane = tid & 63;
    int wm = (wave >> 1) * 64, wn = (wave & 1) * 64;
    int r = lane & 15, g = lane >> 4;
    float4v acc[4][4];
    #pragma unroll
    for (int i = 0; i < 4; ++i)
        #pragma unroll
        for (int j = 0; j < 4; ++j) acc[i][j] = (float4v){0.f, 0.f, 0.f, 0.f};

    for (int k0 = 0; k0 < K; k0 += 32) {
        #pragma unroll
        for (int it = 0; it < 2; ++it) {
            int cbase = wave * 64 + it * 256;
            int rowbase = cbase >> 2;
            int row = rowbase + (lane >> 2);
            int ch = (lane & 3) ^ (row & 3);
            const _Float16* ga = W  + (size_t)(m0 + row) * K + k0 + ch * 8;
            const _Float16* gb = Xb + (size_t)(n0 + row) * K + k0 + ch * 8;
            __builtin_amdgcn_global_load_lds(
                (const __attribute__((address_space(1))) void*)ga,
                (__attribute__((address_space(3))) void*)(As + rowbase * 32), 16, 0, 0);
            __builtin_amdgcn_global_load_lds(
                (const __attribute__((address_space(1))) void*)gb,
                (__attribute__((address_space(3))) void*)(Bs + rowbase * 32), 16, 0, 0);
        }
        __syncthreads();
        half8v af[4], bf[4];
        #pragma unroll
        for (int mt = 0; mt < 4; ++mt) {
            int row = wm + mt * 16 + r;
            af[mt] = *(const half8v*)(As + row * 32 + ((g ^ (row & 3)) << 3));
        }
        #pragma unroll
        for (int nt = 0; nt < 4; ++nt) {
            int row = wn + nt * 16 + r;
            bf[nt] = *(const half8v*)(Bs + row * 32 + ((g ^ (row & 3)) << 3));
        }
        #pragma unroll
        for (int mt = 0; mt < 4; ++mt)
            #pragma unroll
            for (int nt = 0; nt < 4; ++nt)
                acc[mt][nt] = __builtin_amdgcn_mfma_f32_16x16x32_f16(af[mt], bf[nt], acc[mt][nt], 0, 0, 0);
        __syncthreads();
    }
    #pragma unroll
    for (int mt = 0; mt < 4; ++mt) {
        int m_base = m0 + wm + mt * 16 + g * 4;
        float bb[4];
        #pragma unroll
        for (int rr = 0; rr < 4; ++rr) bb[rr] = bias[m_base + rr];
        #pragma unroll
        for (int nt = 0; nt < 4; ++nt) {
            int n = n0 + wn + nt * 16 + r;
            half4v hv;
            #pragma unroll
            for (int rr = 0; rr < 4; ++rr)
                hv[rr] = (_Float16)(acc[mt][nt][rr] + bb[rr]);
            *(half4v*)(Y + ((size_t)b * NTS + n) * M + m_base) = hv;
        }
    }
}

// ---------------- residual GEMM with fused LayerNorm epilogue ----------------
// Block = full channel column: M=256 x N=32 tile -> 512 blocks (2/CU) so a
// co-resident block covers barrier drains (R7: 1 block/CU => 90% stall).
// dec = src + W.X + bias (f32); LN over channels -> s2 fp16 (+ qk = s2+pos).
template<bool POS>
__global__ __launch_bounds__(256) void gemm_res_ln(
        const _Float16* __restrict__ W, const float* __restrict__ bias,
        const _Float16* __restrict__ X, const float* __restrict__ src,
        float* __restrict__ dec, const float* __restrict__ gam,
        const float* __restrict__ bet, const float* __restrict__ pos,
        _Float16* __restrict__ s2, _Float16* __restrict__ qk, int K) {
    __shared__ _Float16 As[256 * 32];   // 16 KB
    __shared__ _Float16 Bs[32 * 32];    // 2 KB
    __shared__ float sumS[4][32], sumQ[4][32];
    __shared__ float meanL[32], rstdL[32];
    int b  = blockIdx.z;
    int n0 = blockIdx.x * 32;
    const _Float16* Xb = X + (size_t)b * NTS * K;
    int tid = threadIdx.x;
    int wave = tid >> 6, lane = tid & 63;
    int wm = wave * 64;
    int r = lane & 15, g = lane >> 4;
    float4v acc[4][2];
    #pragma unroll
    for (int i = 0; i < 4; ++i)
        #pragma unroll
        for (int j = 0; j < 2; ++j) acc[i][j] = (float4v){0.f, 0.f, 0.f, 0.f};

    for (int k0 = 0; k0 < K; k0 += 32) {
        // A-tile: 256 rows x 32 k = 1024 chunks (4 rounds)
        #pragma unroll
        for (int it = 0; it < 4; ++it) {
            int cbase = wave * 64 + it * 256;
            int rowbase = cbase >> 2;
            int row = rowbase + (lane >> 2);
            int ch = (lane & 3) ^ (row & 3);
            const _Float16* ga = W + (size_t)row * K + k0 + ch * 8;
            __builtin_amdgcn_global_load_lds(
                (const __attribute__((address_space(1))) void*)ga,
                (__attribute__((address_space(3))) void*)(As + rowbase * 32), 16, 0, 0);
        }
        // B-tile: 32 rows x 32 k = 128 chunks (waves 0-1)
        if (wave < 2) {
            int cbase = wave * 64;
            int rowbase = cbase >> 2;
            int row = rowbase + (lane >> 2);
            int ch = (lane & 3) ^ (row & 3);
            const _Float16* gb = Xb + (size_t)(n0 + row) * K + k0 + ch * 8;
            __builtin_amdgcn_global_load_lds(
                (const __attribute__((address_space(1))) void*)gb,
                (__attribute__((address_space(3))) void*)(Bs + rowbase * 32), 16, 0, 0);
        }
        __syncthreads();
        half8v af[4], bf[2];
        #pragma unroll
        for (int mt = 0; mt < 4; ++mt) {
            int row = wm + mt * 16 + r;
            af[mt] = *(const half8v*)(As + row * 32 + ((g ^ (row & 3)) << 3));
        }
        #pragma unroll
        for (int nt = 0; nt < 2; ++nt) {
            int row = nt * 16 + r;
            bf[nt] = *(const half8v*)(Bs + row * 32 + ((g ^ (row & 3)) << 3));
        }
        #pragma unroll
        for (int mt = 0; mt < 4; ++mt)
            #pragma unroll
            for (int nt = 0; nt < 2; ++nt)
                acc[mt][nt] = __builtin_amdgcn_mfma_f32_16x16x32_f16(af[mt], bf[nt], acc[mt][nt], 0, 0, 0);
        __syncthreads();
    }

    const float* Sd = src + (size_t)b * C_ * NTS;
    float* Dd = dec + (size_t)b * C_ * NTS;
    #pragma unroll
    for (int mt = 0; mt < 4; ++mt) {
        int mb = wm + mt * 16 + g * 4;
        float bb[4];
        #pragma unroll
        for (int rr = 0; rr < 4; ++rr) bb[rr] = bias[mb + rr];
        #pragma unroll
        for (int nt = 0; nt < 2; ++nt) {
            int n = n0 + nt * 16 + r;
            #pragma unroll
            for (int rr = 0; rr < 4; ++rr) {
                size_t o = (size_t)(mb + rr) * NTS + n;
                float v = Sd[o] + acc[mt][nt][rr] + bb[rr];
                acc[mt][nt][rr] = v;
                Dd[o] = v;
            }
        }
    }
    // LN stats: per-n sums over this wave's 64 m, then cross-wave
    #pragma unroll
    for (int nt = 0; nt < 2; ++nt) {
        float ps = 0.f, pq = 0.f;
        #pragma unroll
        for (int mt = 0; mt < 4; ++mt)
            #pragma unroll
            for (int rr = 0; rr < 4; ++rr) {
                float v = acc[mt][nt][rr];
                ps += v; pq += v * v;
            }
        ps += __shfl_xor(ps, 16, 64); pq += __shfl_xor(pq, 16, 64);
        ps += __shfl_xor(ps, 32, 64); pq += __shfl_xor(pq, 32, 64);
        if (g == 0) { sumS[wave][nt * 16 + r] = ps; sumQ[wave][nt * 16 + r] = pq; }
    }
    __syncthreads();
    if (tid < 32) {
        float s = sumS[0][tid] + sumS[1][tid] + sumS[2][tid] + sumS[3][tid];
        float q = sumQ[0][tid] + sumQ[1][tid] + sumQ[2][tid] + sumQ[3][tid];
        float mean = s * (1.0f / C_);
        float var  = q * (1.0f / C_) - mean * mean;
        meanL[tid] = mean;
        rstdL[tid] = rsqrtf(var + 1e-5f);
    }
    __syncthreads();
    const float* Pb = POS ? pos + (size_t)b * C_ * NTS : nullptr;
    #pragma unroll
    for (int mt = 0; mt < 4; ++mt) {
        int mb = wm + mt * 16 + g * 4;
        float gm[4], be[4];
        #pragma unroll
        for (int rr = 0; rr < 4; ++rr) { gm[rr] = gam[mb + rr]; be[rr] = bet[mb + rr]; }
        #pragma unroll
        for (int nt = 0; nt < 2; ++nt) {
            int n = n0 + nt * 16 + r;
            float mean = meanL[nt * 16 + r], rstd = rstdL[nt * 16 + r];
            half4v hv, hq;
            #pragma unroll
            for (int rr = 0; rr < 4; ++rr) {
                float y = (acc[mt][nt][rr] - mean) * rstd * gm[rr] + be[rr];
                hv[rr] = (_Float16)y;
                if (POS) hq[rr] = (_Float16)(y + Pb[(size_t)(mb + rr) * NTS + n]);
            }
            *(half4v*)(s2 + ((size_t)b * NTS + n) * C_ + mb) = hv;
            if (POS) *(half4v*)(qk + ((size_t)b * NTS + n) * C_ + mb) = hq;
        }
    }
}

// ---------------- gate bits + counts precompute ----------------
__global__ __launch_bounds__(256) void gate_kernel(const float* __restrict__ coord,
                                                   const int* __restrict__ mask,
                                                   unsigned long long* __restrict__ gwb,
                                                   int* __restrict__ ucb,
                                                   unsigned long long* __restrict__ umb) {
    int wid  = blockIdx.x * 4 + (threadIdx.x >> 6);   // bt*512 + q
    int lane = threadIdx.x & 63;
    int q  = wid & 511;
    int bt = wid >> 9;
    const float* cb = coord + (size_t)bt * S_ * 3;
    const int* mrow = mask + (size_t)bt * S_;
    float cq0 = cb[q*3+0], cq1 = cb[q*3+1], cq2 = cb[q*3+2];
    int ucnt = 0;
    for (int i = 0; i < 8; ++i) {
        int k = i * 64 + lane;
        float dx = cq0 - cb[k*3+0];
        float dy = cq1 - cb[k*3+1];
        float dz = cq2 - cb[k*3+2];
        bool near = (dx*dx + dy*dy + dz*dz) < 625.0f;
        bool um = (mrow[k] == 0);
        unsigned long long gm = __ballot(near && um);
        unsigned long long un = __ballot(um);
        if (lane == 0) {
            gwb[(size_t)wid*8 + i] = gm;
            ucnt += __popcll(un);
            if (q == 0) umb[bt*8 + i] = un;
        }
    }
    if (lane == 0) ucb[wid] = ucnt;
}

// ---------------- sparse distance-gated attention ----------------
// One 512-thread block per (b,h,t): stages K/V ONCE (R7 staged twice).
__global__ __launch_bounds__(512) void attn_kernel(
        const _Float16* __restrict__ qk, const _Float16* __restrict__ v,
        const unsigned long long* __restrict__ gwb, const int* __restrict__ ucb,
        const unsigned long long* __restrict__ umb, _Float16* __restrict__ out) {
    __shared__ _Float16 KV[S_ * 72];    // 72 KB: row s = [K 32 | V 32 | pad 8]
    __shared__ float Upart[16][32];
    __shared__ float Ufin[HD_];
    int bid = blockIdx.x;               // b*H*T + h*T + t? (use b<<7 | h<<4 | t)
    int t = bid & (T_-1), h = (bid >> 4) & (H_-1), b = bid >> 7;
    int tid = threadIdx.x;
    int bt = b * T_ + t;
    const _Float16* kg = qk + ((size_t)bt * S_) * QKM + 256 + h * HD_;
    const _Float16* vg = v  + ((size_t)bt * S_) * C_  + h * HD_;

    #pragma unroll
    for (int it = 0; it < 4; ++it) {
        int c = tid + it * 512;
        int s = c >> 2, ch = c & 3;
        *(half8v*)(KV + s * 72 + ch * 8)      = *(const half8v*)(kg + (size_t)s * QKM + ch * 8);
        *(half8v*)(KV + s * 72 + 32 + ch * 8) = *(const half8v*)(vg + (size_t)s * C_ + ch * 8);
    }

    int qi = tid;
    h8u qa[4];
    {
        const half8v* qp = (const half8v*)(qk + ((size_t)bt * S_ + qi) * QKM + h * HD_);
        #pragma unroll
        for (int i = 0; i < 4; ++i) qa[i].v = qp[i];
    }
    __syncthreads();

    {   // U partials: thread (d, grp) sums its 32-key group (16 groups)
        int d = tid & 31, grp = tid >> 5;
        unsigned long long um = umb[bt*8 + (grp >> 1)];
        uint32_t umw = (uint32_t)(um >> ((grp & 1) * 32));
        float s = 0.f;
        for (int kk = 0; kk < 32; ++kk)
            if ((umw >> kk) & 1) s += (float)KV[(grp*32 + kk) * 72 + 32 + d];
        Upart[grp][d] = s;
    }
    __syncthreads();
    if (tid < HD_) {
        float s = 0.f;
        #pragma unroll
        for (int gp = 0; gp < 16; ++gp) s += Upart[gp][tid];
        Ufin[tid] = s;
    }
    __syncthreads();

    const unsigned long long* gw8 = gwb + ((size_t)bt * S_ + qi) * 8;
    float O[HD_];
    #pragma unroll
    for (int d = 0; d < HD_; ++d) O[d] = 0.f;
    float l = (float)ucb[(size_t)bt * S_ + qi];

    for (int w = 0; w < 8; ++w) {
        unsigned long long gw = gw8[w];
        while (gw) {
            int j = __builtin_ctzll(gw);
            gw &= gw - 1;
            const _Float16* row = KV + (w * 64 + j) * 72;
            h8u k0, k1, k2, k3;
            k0.v = *(const half8v*)(row);
            k1.v = *(const half8v*)(row + 8);
            k2.v = *(const half8v*)(row + 16);
            k3.v = *(const half8v*)(row + 24);
            float s = 0.f;
            #pragma unroll
            for (int i = 0; i < 4; ++i) {
                s = __builtin_amdgcn_fdot2(k0.h[i], qa[0].h[i], s, false);
                s = __builtin_amdgcn_fdot2(k1.h[i], qa[1].h[i], s, false);
                s = __builtin_amdgcn_fdot2(k2.h[i], qa[2].h[i], s, false);
                s = __builtin_amdgcn_fdot2(k3.h[i], qa[3].h[i], s, false);
            }
            s *= 0.17677669529663687f;
            float e = __expf(fminf(s, 80.f));
            float em1 = e - 1.f;
            l += em1;
            half8v v0 = *(const half8v*)(row + 32);
            half8v v1 = *(const half8v*)(row + 40);
            half8v v2 = *(const half8v*)(row + 48);
            half8v v3 = *(const half8v*)(row + 56);
            #pragma unroll
            for (int d = 0; d < 8; ++d) {
                O[d]      = fmaf((float)v0[d], em1, O[d]);
                O[d + 8]  = fmaf((float)v1[d], em1, O[d + 8]);
                O[d + 16] = fmaf((float)v2[d], em1, O[d + 16]);
                O[d + 24] = fmaf((float)v3[d], em1, O[d + 24]);
            }
        }
    }
    float invl = 1.0f / l;
    _Float16* orow = out + ((size_t)bt * S_ + qi) * C_ + h * HD_;
    #pragma unroll
    for (int c0 = 0; c0 < 4; ++c0) {
        half8v hv;
        #pragma unroll
        for (int j = 0; j < 8; ++j)
            hv[j] = (_Float16)((O[c0*8+j] + Ufin[c0*8+j]) * invl);
        *(half8v*)(orow + c0 * 8) = hv;
    }
}

// ---------------- driver ----------------
extern "C" void kernel_launch(void* const* d_in, const int* in_sizes, int n_in,
                              void* d_out, int out_size, void* d_ws, size_t ws_size,
                              hipStream_t stream) {
    const float* decoder = (const float*)d_in[0];
    const float* encoder = (const float*)d_in[1];
    const float* pos     = (const float*)d_in[2];
    const float* coord   = (const float*)d_in[3];
    const int*   mask    = (const int*)d_in[4];
    const float* Wq = (const float*)d_in[5],  *bq = (const float*)d_in[6];
    const float* Wk = (const float*)d_in[7],  *bk = (const float*)d_in[8];
    const float* Wv = (const float*)d_in[9],  *bv = (const float*)d_in[10];
    const float* Wo = (const float*)d_in[11], *bo = (const float*)d_in[12];
    const float* W1 = (const float*)d_in[13], *b1 = (const float*)d_in[14];
    const float* W2 = (const float*)d_in[15], *b2 = (const float*)d_in[16];
    const float* ln_g = (const float*)d_in[17], *ln_b = (const float*)d_in[18];

    float* dec = (float*)d_out;

    size_t actsz = (size_t)B_ * NTS * C_;          // 4.19M halves (8.4 MB)
    _Float16* qkT  = (_Float16*)d_ws;              // 1
    _Float16* qkT2 = qkT + actsz;                  // 2 (fused Q|K output)
    _Float16* vT   = qkT2 + 2*actsz;               // 1
    _Float16* s2T  = vT + actsz;                   // 1 (LN outputs)
    _Float16* aT   = s2T + actsz;                  // 1 (attn output)
    _Float16* encT = aT + actsz;                   // 1 (enc+pos, layer-invariant)
    _Float16* hT   = encT + actsz;                 // 4 (FFN hidden, dedicated)
    _Float16* whqk = hT + 4*actsz;
    _Float16* whv  = whqk + (size_t)L_*QKM*C_;
    _Float16* who  = whv + (size_t)L_*C_*C_;
    _Float16* wh1  = who + (size_t)L_*C_*C_;
    _Float16* wh2  = wh1 + (size_t)L_*DFF_*C_;
    float* bqk = (float*)(wh2 + (size_t)L_*C_*DFF_);
    unsigned long long* gwb = (unsigned long long*)(bqk + L_*QKM);
    int* ucb = (int*)(gwb + (size_t)B_*T_*S_*8);
    unsigned long long* umb = (unsigned long long*)(ucb + (size_t)B_*T_*S_);

    dim3 gGridQKV(NTS/128, 6, B_);        // fused QK(4) + V(2)
    dim3 gGridC(NTS/128, C_/128, B_);     // (64, 2, 2)
    dim3 gGridF(NTS/128, DFF_/128, B_);   // (64, 8, 2)
    dim3 gGridRL(NTS/32, 1, B_);          // (256, 1, 2) res+LN fused, 2 blocks/CU
    dim3 lnGrid(B_ * NTS / 32);
    dim3 attnGrid(B_ * H_ * T_);          // 256 blocks x 512 threads
    dim3 gateGrid(B_ * T_ * S_ / 4);
    dim3 prepGrid(6148);

    gate_kernel<<<gateGrid, 256, 0, stream>>>(coord, mask, gwb, ucb, umb);
    prep_kernel<<<prepGrid, 256, 0, stream>>>(Wq, Wk, Wv, Wo, W1, W2, bq, bk,
                                              whqk, whv, who, wh1, wh2, bqk);
    addt_kernel<<<lnGrid, 256, 0, stream>>>(encoder, pos, encT);   // layer-invariant

    for (int l = 0; l < L_; ++l) {
        const _Float16* whqk_l = whqk + (size_t)l*QKM*C_; const float* bqk_l = bqk + l*QKM;
        const _Float16* whv_l = whv + (size_t)l*C_*C_;  const float* bv_l = bv + l*C_;
        const _Float16* who_l = who + (size_t)l*C_*C_;  const float* bo_l = bo + l*C_;
        const _Float16* wh1_l = wh1 + (size_t)l*DFF_*C_; const float* b1_l = b1 + l*DFF_;
        const _Float16* wh2_l = wh2 + (size_t)l*C_*DFF_; const float* b2_l = b2 + l*C_;
        const float* g1 = ln_g + ((size_t)l*3 + 1)*C_; const float* e1 = ln_b + ((size_t)l*3 + 1)*C_;
        const float* g2 = ln_g + ((size_t)l*3 + 2)*C_; const float* e2 = ln_b + ((size_t)l*3 + 2)*C_;

        // ---- block A: qk = LN0(x)+pos, v-input = LN0(x)
        if (l == 0) {
            const float* g0 = ln_g; const float* e0 = ln_b;
            ln_t<true><<<lnGrid, 256, 0, stream>>>(decoder, g0, e0, pos, s2T, qkT);
        }
        gemm_qkv<<<gGridQKV, 256, 0, stream>>>(whqk_l, bqk_l, qkT, qkT2,
                                               whv_l, bv_l, s2T, vT);
        attn_kernel<<<attnGrid, 512, 0, stream>>>(qkT2, vT, gwb, ucb, umb, aT);
        gemm_res_ln<false><<<gGridRL, 256, 0, stream>>>(who_l, bo_l, aT,
                (l == 0) ? decoder : dec, dec, g1, e1, nullptr, s2T, nullptr, C_);

        // ---- block B: qk = enc+pos (precomputed encT), v-input = LN1(dec)=s2T
        gemm_qkv<<<gGridQKV, 256, 0, stream>>>(whqk_l, bqk_l, encT, qkT2,
                                               whv_l, bv_l, s2T, vT);
        attn_kernel<<<attnGrid, 512, 0, stream>>>(qkT2, vT, gwb, ucb, umb, aT);
        gemm_res_ln<false><<<gGridRL, 256, 0, stream>>>(who_l, bo_l, aT,
                dec, dec, g2, e2, nullptr, s2T, nullptr, C_);

        // ---- FFN
        gemm_mfma<2><<<gGridF, 256, 0, stream>>>(wh1_l, b1_l, s2T, nullptr, hT, DFF_, C_);
        if (l + 1 < L_) {
            const float* g0n = ln_g + ((size_t)(l+1)*3 + 0)*C_;
            const float* e0n = ln_b + ((size_t)(l+1)*3 + 0)*C_;
            gemm_res_ln<true><<<gGridRL, 256, 0, stream>>>(wh2_l, b2_l, hT,
                    dec, dec, g0n, e0n, pos, s2T, qkT, DFF_);
        } else {
            gemm_mfma<1><<<gGridC, 256, 0, stream>>>(wh2_l, b2_l, hT, dec, dec, C_, DFF_);
        }
    }
}